// Round 3
// baseline (2218.014 us; speedup 1.0000x reference)
//
#include <hip/hip_runtime.h>
#include <hip/hip_fp16.h>
#include <math.h>

// Problem constants (match reference)
constexpr int NN = 50000;    // nodes
constexpr int NE = 800000;   // undirected edges E0
constexpr int KS = 10;       // iterations
constexpr float LAM = 3.0f;  // lambda

struct __align__(16) EInfo { int r, c; float a, b; };  // r=max, c=min, a=dis[r], b=dis[c]

// ---------------- precompute kernels ----------------

__global__ __launch_bounds__(256) void count_kernel(
    const int* __restrict__ src, const int* __restrict__ dst,
    int* __restrict__ cA) {
  int e = blockIdx.x * 256 + threadIdx.x;
  if (e >= NE) return;
  atomicAdd(&cA[src[e]], 1);
  atomicAdd(&cA[dst[e]], 1);
}

__global__ __launch_bounds__(256) void dis_kernel(
    const int* __restrict__ cA, float* __restrict__ dis) {
  int i = blockIdx.x * 256 + threadIdx.x;
  if (i < NN) dis[i] = 1.0f / sqrtf((float)(cA[i] + 1)); // deg incl. self loop
}

__global__ __launch_bounds__(256) void rcab_kernel(
    const int* __restrict__ src, const int* __restrict__ dst,
    const float* __restrict__ dis, EInfo* __restrict__ rcab) {
  int e = blockIdx.x * 256 + threadIdx.x;
  if (e >= NE) return;
  int s = src[e], d = dst[e];
  int r = s > d ? s : d;
  int c = s > d ? d : s;
  EInfo ei; ei.r = r; ei.c = c; ei.a = dis[r]; ei.b = dis[c];
  rcab[e] = ei;
}

// exclusive scan of counts -> ptr (N+1) and cursor copy (single block)
__global__ __launch_bounds__(1024) void scan_kernel(
    const int* __restrict__ cnt, int* __restrict__ ptr, int* __restrict__ cur) {
  __shared__ int part[1024];
  int t = threadIdx.x;
  const int per = (NN + 1023) / 1024;  // 49
  int s0 = t * per;
  int s1 = s0 + per; if (s1 > NN) s1 = NN;
  if (s0 > NN) s0 = NN;
  int s = 0;
  for (int i = s0; i < s1; ++i) s += cnt[i];
  part[t] = s;
  __syncthreads();
  for (int off = 1; off < 1024; off <<= 1) {
    int v = part[t];
    int a = (t >= off) ? part[t - off] : 0;
    __syncthreads();
    part[t] = v + a;
    __syncthreads();
  }
  int base = (t == 0) ? 0 : part[t - 1];
  for (int i = s0; i < s1; ++i) {
    int cv = cnt[i];
    ptr[i] = base;
    cur[i] = base;
    base += cv;
  }
  if (s1 == NN) ptr[NN] = base;  // trailing threads all write the total
}

// Incident-edge CSR entries: (edge_id | SIGNBIT). SIGNBIT set iff this node
// is r = max(s,d) (the +1 side of the incidence row). Split into two kernels
// (s-side / d-side) for profiling visibility; cursors are shared.
__global__ __launch_bounds__(256) void scatterS_kernel(
    const int* __restrict__ src, const int* __restrict__ dst,
    int* __restrict__ uA, int* __restrict__ ents) {
  int e = blockIdx.x * 256 + threadIdx.x;
  if (e >= NE) return;
  int s = src[e], d = dst[e];
  int p = atomicAdd(&uA[s], 1);
  ents[p] = e | ((s >= d) ? 0x80000000 : 0);
}

__global__ __launch_bounds__(256) void scatterD_kernel(
    const int* __restrict__ src, const int* __restrict__ dst,
    int* __restrict__ uA, int* __restrict__ ents) {
  int e = blockIdx.x * 256 + threadIdx.x;
  if (e >= NE) return;
  int s = src[e], d = dst[e];
  int p = atomicAdd(&uA[d], 1);
  ents[p] = e | ((d > s) ? 0x80000000 : 0);
}

// ---------------- per-step kernels ----------------
// One wave (64 lanes) per node row; lanes split as 4 groups x 16.
// Group g walks list entries jb+g, jb+g+4, ... (x2 unrolled => two indirect
// chains in flight); lane l covers float4 features [4l..4l+3]. Butterfly
// shfl_xor(16/32) folds the 4 groups.

// y = 0.25*h + 0.75*(D^-1/2 (A+I) D^-1/2) xk ;  XB = x_bar = y - 0.25*U_old
// (FIRST: U_old == 0 -> XB = y)
template <int FIRST>
__global__ __launch_bounds__(256) void adj_kernel(
    const float* __restrict__ Xk, const float* __restrict__ H,
    const float* __restrict__ U, const float* __restrict__ dis,
    const int* __restrict__ pA, const int* __restrict__ ents,
    const EInfo* __restrict__ rcab, float* __restrict__ XB) {
  int w = (int)((blockIdx.x * 256u + threadIdx.x) >> 6);
  if (w >= NN) return;
  int lane = threadIdx.x & 63;
  int g = lane >> 4, l = lane & 15;
  const float4* X4 = (const float4*)Xk;
  float ax = 0.f, ay = 0.f, az = 0.f, aw = 0.f;
  int jb = pA[w], je = pA[w + 1];
  int j = jb + g;
  for (; j + 4 < je; j += 8) {
    int raw0 = ents[j];
    int raw1 = ents[j + 4];
    EInfo e0 = rcab[raw0 & 0x7FFFFFFF];
    EInfo e1 = rcab[raw1 & 0x7FFFFFFF];
    int   c0 = (raw0 < 0) ? e0.c : e0.r;
    float w0 = (raw0 < 0) ? e0.b : e0.a;
    int   c1 = (raw1 < 0) ? e1.c : e1.r;
    float w1 = (raw1 < 0) ? e1.b : e1.a;
    float4 x0 = X4[c0 * 16 + l];
    float4 x1 = X4[c1 * 16 + l];
    ax = fmaf(w0, x0.x, ax); ay = fmaf(w0, x0.y, ay);
    az = fmaf(w0, x0.z, az); aw = fmaf(w0, x0.w, aw);
    ax = fmaf(w1, x1.x, ax); ay = fmaf(w1, x1.y, ay);
    az = fmaf(w1, x1.z, az); aw = fmaf(w1, x1.w, aw);
  }
  if (j < je) {
    int raw0 = ents[j];
    EInfo e0 = rcab[raw0 & 0x7FFFFFFF];
    int   c0 = (raw0 < 0) ? e0.c : e0.r;
    float w0 = (raw0 < 0) ? e0.b : e0.a;
    float4 x0 = X4[c0 * 16 + l];
    ax = fmaf(w0, x0.x, ax); ay = fmaf(w0, x0.y, ay);
    az = fmaf(w0, x0.z, az); aw = fmaf(w0, x0.w, aw);
  }
  ax += __shfl_xor(ax, 16, 64); ay += __shfl_xor(ay, 16, 64);
  az += __shfl_xor(az, 16, 64); aw += __shfl_xor(aw, 16, 64);
  ax += __shfl_xor(ax, 32, 64); ay += __shfl_xor(ay, 32, 64);
  az += __shfl_xor(az, 32, 64); aw += __shfl_xor(aw, 32, 64);
  if (g == 0) {
    float di = dis[w];
    int idx = w * 16 + l;
    float4 xs = X4[idx];
    float4 h4 = ((const float4*)H)[idx];
    float4 y4;
    y4.x = 0.25f * h4.x + 0.75f * di * fmaf(di, xs.x, ax);
    y4.y = 0.25f * h4.y + 0.75f * di * fmaf(di, xs.y, ay);
    y4.z = 0.25f * h4.z + 0.75f * di * fmaf(di, xs.z, az);
    y4.w = 0.25f * h4.w + 0.75f * di * fmaf(di, xs.w, aw);
    float4 xb;
    if (FIRST) {
      xb = y4;
    } else {
      float4 u4 = ((const float4*)U)[idx];
      xb.x = y4.x - 0.25f * u4.x;
      xb.y = y4.y - 0.25f * u4.y;
      xb.z = y4.z - 0.25f * u4.z;
      xb.w = y4.w - 0.25f * u4.w;
    }
    ((float4*)XB)[idx] = xb;
  }
}

// z <- proj_L21( z + 2*(a*xb[r] - b*xb[c]) ), in place, Z stored fp16.
// Wave = 4 edge rows (one per 16-lane group).
template <int FIRST>
__global__ __launch_bounds__(256) void zstep_kernel(
    __half* __restrict__ Z, const float* __restrict__ XB,
    const EInfo* __restrict__ rcab) {
  int w = (int)((blockIdx.x * 256u + threadIdx.x) >> 6);
  int lane = threadIdx.x & 63;
  int g = lane >> 4, l = lane & 15;
  int e = w * 4 + g;
  if (e >= NE) return;
  EInfo ei = rcab[e];
  const float4* X4 = (const float4*)XB;
  uint2* Z2 = (uint2*)Z;
  int zi = e * 16 + l;
  float4 xr = X4[ei.r * 16 + l];
  float4 xc = X4[ei.c * 16 + l];
  float zx, zy, zz, zw;
  if (FIRST) {
    zx = zy = zz = zw = 0.f;   // z0 = 0 (never read poisoned ws)
  } else {
    uint2 zu = Z2[zi];
    float2 f0 = __half22float2(*(const __half2*)&zu.x);
    float2 f1 = __half22float2(*(const __half2*)&zu.y);
    zx = f0.x; zy = f0.y; zz = f1.x; zw = f1.y;
  }
  zx += 2.0f * (ei.a * xr.x - ei.b * xc.x);
  zy += 2.0f * (ei.a * xr.y - ei.b * xc.y);
  zz += 2.0f * (ei.a * xr.z - ei.b * xc.z);
  zw += 2.0f * (ei.a * xr.w - ei.b * xc.w);
  float ss = zx * zx + zy * zy + zz * zz + zw * zw;
  ss += __shfl_xor(ss, 1, 64);
  ss += __shfl_xor(ss, 2, 64);
  ss += __shfl_xor(ss, 4, 64);
  ss += __shfl_xor(ss, 8, 64);   // 16-lane group sum (stays inside group)
  float rn = sqrtf(ss);
  float sc = (rn > LAM) ? (LAM / rn) : 1.0f;
  __half2 o0 = __floats2half2_rn(sc * zx, sc * zy);
  __half2 o1 = __floats2half2_rn(sc * zz, sc * zw);
  uint2 outu;
  outu.x = *(const unsigned*)&o0;
  outu.y = *(const unsigned*)&o1;
  Z2[zi] = outu;
}

// u_new = dis_i * sum_{e incident i} sign_e * z_e ;
// y = XB + 0.25*U_old (reconstructed); Xout = y - 0.25*u_new; U <- u_new.
template <int FIRST, int LAST>
__global__ __launch_bounds__(256) void incT_kernel(
    const __half* __restrict__ Z, const float* __restrict__ XB,
    const float* __restrict__ dis,
    const int* __restrict__ pA, const int* __restrict__ ents,
    float* __restrict__ U, float* __restrict__ Xout) {
  int w = (int)((blockIdx.x * 256u + threadIdx.x) >> 6);
  if (w >= NN) return;
  int lane = threadIdx.x & 63;
  int g = lane >> 4, l = lane & 15;
  const uint2* Z2 = (const uint2*)Z;
  float ax = 0.f, ay = 0.f, az = 0.f, aw = 0.f;
  int jb = pA[w], je = pA[w + 1];
  int j = jb + g;
  for (; j + 4 < je; j += 8) {
    int raw0 = ents[j];
    int raw1 = ents[j + 4];
    uint2 zu0 = Z2[(raw0 & 0x7FFFFFFF) * 16 + l];
    uint2 zu1 = Z2[(raw1 & 0x7FFFFFFF) * 16 + l];
    float s0 = (raw0 < 0) ? 1.0f : -1.0f;
    float s1 = (raw1 < 0) ? 1.0f : -1.0f;
    float2 a0 = __half22float2(*(const __half2*)&zu0.x);
    float2 b0 = __half22float2(*(const __half2*)&zu0.y);
    float2 a1 = __half22float2(*(const __half2*)&zu1.x);
    float2 b1 = __half22float2(*(const __half2*)&zu1.y);
    ax = fmaf(s0, a0.x, ax); ay = fmaf(s0, a0.y, ay);
    az = fmaf(s0, b0.x, az); aw = fmaf(s0, b0.y, aw);
    ax = fmaf(s1, a1.x, ax); ay = fmaf(s1, a1.y, ay);
    az = fmaf(s1, b1.x, az); aw = fmaf(s1, b1.y, aw);
  }
  if (j < je) {
    int raw0 = ents[j];
    uint2 zu0 = Z2[(raw0 & 0x7FFFFFFF) * 16 + l];
    float s0 = (raw0 < 0) ? 1.0f : -1.0f;
    float2 a0 = __half22float2(*(const __half2*)&zu0.x);
    float2 b0 = __half22float2(*(const __half2*)&zu0.y);
    ax = fmaf(s0, a0.x, ax); ay = fmaf(s0, a0.y, ay);
    az = fmaf(s0, b0.x, az); aw = fmaf(s0, b0.y, aw);
  }
  ax += __shfl_xor(ax, 16, 64); ay += __shfl_xor(ay, 16, 64);
  az += __shfl_xor(az, 16, 64); aw += __shfl_xor(aw, 16, 64);
  ax += __shfl_xor(ax, 32, 64); ay += __shfl_xor(ay, 32, 64);
  az += __shfl_xor(az, 32, 64); aw += __shfl_xor(aw, 32, 64);
  if (g == 0) {
    float di = dis[w];
    int idx = w * 16 + l;
    float4 u;
    u.x = di * ax; u.y = di * ay; u.z = di * az; u.w = di * aw;
    float4 xb = ((const float4*)XB)[idx];
    float4 y4;
    if (FIRST) {
      y4 = xb;  // U_old == 0
    } else {
      float4 uo = ((const float4*)U)[idx];
      y4.x = xb.x + 0.25f * uo.x;
      y4.y = xb.y + 0.25f * uo.y;
      y4.z = xb.z + 0.25f * uo.z;
      y4.w = xb.w + 0.25f * uo.w;
    }
    if (!LAST) ((float4*)U)[idx] = u;  // dead after final step
    float4 o;
    o.x = y4.x - 0.25f * u.x;
    o.y = y4.y - 0.25f * u.y;
    o.z = y4.z - 0.25f * u.z;
    o.w = y4.w - 0.25f * u.w;
    ((float4*)Xout)[idx] = o;
  }
}

// ---------------- launch ----------------

extern "C" void kernel_launch(void* const* d_in, const int* in_sizes, int n_in,
                              void* d_out, int out_size, void* d_ws, size_t ws_size,
                              hipStream_t stream) {
  const float* x  = (const float*)d_in[0];
  const int* esrc = (const int*)d_in[1];
  const int* edst = (const int*)d_in[2];
  float* out = (float*)d_out;

  char* base = (char*)d_ws;
  size_t off = 0;
  auto carve = [&](size_t bytes) -> void* {
    void* p = base + off;
    off += (bytes + 255) & ~(size_t)255;
    return p;
  };
  __half* Z  = (__half*)carve((size_t)NE * 64 * 2);  // 102.4 MB, carry state z
  float* XK  = (float*)carve((size_t)NN * 64 * 4);   // current xk
  float* XB  = (float*)carve((size_t)NN * 64 * 4);   // x_bar
  float* U   = (float*)carve((size_t)NN * 64 * 4);   // incT(z), reused next step
  float* dis = (float*)carve((size_t)NN * 4);
  int* cA = (int*)carve((size_t)NN * 4);
  int* pA = (int*)carve((size_t)(NN + 1) * 4);
  int* uA = (int*)carve((size_t)NN * 4);
  int* ents = (int*)carve((size_t)2 * NE * 4);       // 6.4 MB incident CSR
  EInfo* rcab = (EInfo*)carve((size_t)NE * 16);      // 12.8 MB per-edge info
  (void)ws_size; (void)in_sizes; (void)n_in; (void)out_size;

  hipMemsetAsync(cA, 0, NN * 4, stream);

  count_kernel<<<(NE + 255) / 256, 256, 0, stream>>>(esrc, edst, cA);
  dis_kernel<<<(NN + 255) / 256, 256, 0, stream>>>(cA, dis);
  rcab_kernel<<<(NE + 255) / 256, 256, 0, stream>>>(esrc, edst, dis, rcab);
  scan_kernel<<<1, 1024, 0, stream>>>(cA, pA, uA);
  scatterS_kernel<<<(NE + 255) / 256, 256, 0, stream>>>(esrc, edst, uA, ents);
  scatterD_kernel<<<(NE + 255) / 256, 256, 0, stream>>>(esrc, edst, uA, ents);

  const int nodeBlocks = NN * 64 / 256;       // 12500 (one wave/node, exact)
  const int edgeBlocks = (NE / 4) * 64 / 256; // 50000 (wave = 4 edges, exact)

  for (int k = 0; k < KS; ++k) {
    const float* xk = (k == 0) ? x : XK;
    if (k == 0)
      adj_kernel<1><<<nodeBlocks, 256, 0, stream>>>(xk, x, U, dis, pA, ents, rcab, XB);
    else
      adj_kernel<0><<<nodeBlocks, 256, 0, stream>>>(xk, x, U, dis, pA, ents, rcab, XB);

    if (k == 0)
      zstep_kernel<1><<<edgeBlocks, 256, 0, stream>>>(Z, XB, rcab);
    else
      zstep_kernel<0><<<edgeBlocks, 256, 0, stream>>>(Z, XB, rcab);

    float* xout = (k == KS - 1) ? out : XK;
    if (k == 0)
      incT_kernel<1, 0><<<nodeBlocks, 256, 0, stream>>>(Z, XB, dis, pA, ents, U, xout);
    else if (k == KS - 1)
      incT_kernel<0, 1><<<nodeBlocks, 256, 0, stream>>>(Z, XB, dis, pA, ents, U, xout);
    else
      incT_kernel<0, 0><<<nodeBlocks, 256, 0, stream>>>(Z, XB, dis, pA, ents, U, xout);
  }
}

// Round 4
// 1888.041 us; speedup vs baseline: 1.1748x; 1.1748x over previous
//
#include <hip/hip_runtime.h>
#include <hip/hip_fp16.h>
#include <math.h>

// Problem constants (match reference)
constexpr int NN = 50000;    // nodes
constexpr int NE = 800000;   // undirected edges E0
constexpr int KS = 10;       // iterations
constexpr float LAM = 3.0f;  // lambda

constexpr int SCAN_NB = (NN + 255) / 256;  // 196 scan blocks

struct __align__(16) EInfo { int r, c; float a, b; };  // r=max, c=min, a=dis[r], b=dis[c]

// ---------------- precompute kernels ----------------

__global__ __launch_bounds__(256) void count_kernel(
    const int* __restrict__ src, const int* __restrict__ dst,
    int* __restrict__ cA) {
  int e = blockIdx.x * 256 + threadIdx.x;
  if (e >= NE) return;
  atomicAdd(&cA[src[e]], 1);
  atomicAdd(&cA[dst[e]], 1);
}

__global__ __launch_bounds__(256) void dis_kernel(
    const int* __restrict__ cA, float* __restrict__ dis) {
  int i = blockIdx.x * 256 + threadIdx.x;
  if (i < NN) dis[i] = 1.0f / sqrtf((float)(cA[i] + 1)); // deg incl. self loop
}

__global__ __launch_bounds__(256) void rcab_kernel(
    const int* __restrict__ src, const int* __restrict__ dst,
    const float* __restrict__ dis, EInfo* __restrict__ rcab) {
  int e = blockIdx.x * 256 + threadIdx.x;
  if (e >= NE) return;
  int s = src[e], d = dst[e];
  int r = s > d ? s : d;
  int c = s > d ? d : s;
  EInfo ei; ei.r = r; ei.c = c; ei.a = dis[r]; ei.b = dis[c];
  rcab[e] = ei;
}

// ---- hierarchical exclusive scan: A) block sums, B) scan sums, C) emit ----

__global__ __launch_bounds__(256) void scanA_kernel(
    const int* __restrict__ cnt, int* __restrict__ bsum) {
  __shared__ int sm[256];
  int t = threadIdx.x;
  int i = blockIdx.x * 256 + t;
  int v = (i < NN) ? cnt[i] : 0;
  sm[t] = v;
  __syncthreads();
  for (int off = 128; off > 0; off >>= 1) {
    if (t < off) sm[t] += sm[t + off];
    __syncthreads();
  }
  if (t == 0) bsum[blockIdx.x] = sm[0];
}

__global__ __launch_bounds__(256) void scanB_kernel(
    int* __restrict__ bsum, int* __restrict__ boff) {
  __shared__ int sm[256];
  int t = threadIdx.x;
  int v = (t < SCAN_NB) ? bsum[t] : 0;
  sm[t] = v;
  __syncthreads();
  for (int off = 1; off < 256; off <<= 1) {
    int a = (t >= off) ? sm[t - off] : 0;
    __syncthreads();
    sm[t] += a;
    __syncthreads();
  }
  if (t < SCAN_NB) boff[t] = sm[t] - v;  // exclusive
}

__global__ __launch_bounds__(256) void scanC_kernel(
    const int* __restrict__ cnt, const int* __restrict__ boff,
    int* __restrict__ ptr, int* __restrict__ cur) {
  __shared__ int sm[256];
  int t = threadIdx.x;
  int i = blockIdx.x * 256 + t;
  int v = (i < NN) ? cnt[i] : 0;
  sm[t] = v;
  __syncthreads();
  for (int off = 1; off < 256; off <<= 1) {
    int a = (t >= off) ? sm[t - off] : 0;
    __syncthreads();
    sm[t] += a;
    __syncthreads();
  }
  if (i < NN) {
    int ex = boff[blockIdx.x] + sm[t] - v;  // exclusive prefix
    ptr[i] = ex;
    cur[i] = ex;
    if (i == NN - 1) ptr[NN] = ex + v;
  }
}

// Combined incident-edge CSR: per node, int2 (other_endpoint, edge|SIGNBIT).
// SIGNBIT set iff this node is r = max(s,d) (the +1 incidence side).
__global__ __launch_bounds__(256) void scatter_kernel(
    const int* __restrict__ src, const int* __restrict__ dst,
    int* __restrict__ uA, int2* __restrict__ ents) {
  int e = blockIdx.x * 256 + threadIdx.x;
  if (e >= NE) return;
  int s = src[e], d = dst[e];
  int p = atomicAdd(&uA[s], 1);
  ents[p] = make_int2(d, e | ((s >= d) ? 0x80000000 : 0));
  p = atomicAdd(&uA[d], 1);
  ents[p] = make_int2(s, e | ((d > s) ? 0x80000000 : 0));
}

// ---------------- per-step kernels ----------------
// One wave (64 lanes) per node row; lanes split as 4 groups x 16.
// Group g walks entries jb+g, jb+g+4, ... (x2 unrolled => two independent
// depth-2 indirect chains in flight); lane l covers float4 feats [4l..4l+3].
// Butterfly shfl_xor(16/32) folds the 4 groups.

// y = 0.25*h + 0.75*(D^-1/2 (A+I) D^-1/2) xk ;  XB = x_bar = y - 0.25*U_old
template <int FIRST>
__global__ __launch_bounds__(256) void adj_kernel(
    const float* __restrict__ Xk, const float* __restrict__ H,
    const float* __restrict__ U, const float* __restrict__ dis,
    const int* __restrict__ pA, const int2* __restrict__ ents,
    float* __restrict__ XB) {
  int w = (int)((blockIdx.x * 256u + threadIdx.x) >> 6);
  if (w >= NN) return;
  int lane = threadIdx.x & 63;
  int g = lane >> 4, l = lane & 15;
  const float4* X4 = (const float4*)Xk;
  float ax = 0.f, ay = 0.f, az = 0.f, aw = 0.f;
  int jb = pA[w], je = pA[w + 1];
  int j = jb + g;
  for (; j + 4 < je; j += 8) {
    int c0 = ents[j].x;
    int c1 = ents[j + 4].x;
    float w0 = dis[c0];              // small array: L1/L2 hit, runs
    float w1 = dis[c1];              // concurrently with the X4 gather
    float4 x0 = X4[c0 * 16 + l];
    float4 x1 = X4[c1 * 16 + l];
    ax = fmaf(w0, x0.x, ax); ay = fmaf(w0, x0.y, ay);
    az = fmaf(w0, x0.z, az); aw = fmaf(w0, x0.w, aw);
    ax = fmaf(w1, x1.x, ax); ay = fmaf(w1, x1.y, ay);
    az = fmaf(w1, x1.z, az); aw = fmaf(w1, x1.w, aw);
  }
  if (j < je) {
    int c0 = ents[j].x;
    float w0 = dis[c0];
    float4 x0 = X4[c0 * 16 + l];
    ax = fmaf(w0, x0.x, ax); ay = fmaf(w0, x0.y, ay);
    az = fmaf(w0, x0.z, az); aw = fmaf(w0, x0.w, aw);
  }
  ax += __shfl_xor(ax, 16, 64); ay += __shfl_xor(ay, 16, 64);
  az += __shfl_xor(az, 16, 64); aw += __shfl_xor(aw, 16, 64);
  ax += __shfl_xor(ax, 32, 64); ay += __shfl_xor(ay, 32, 64);
  az += __shfl_xor(az, 32, 64); aw += __shfl_xor(aw, 32, 64);
  if (g == 0) {
    float di = dis[w];
    int idx = w * 16 + l;
    float4 xs = X4[idx];
    float4 h4 = ((const float4*)H)[idx];
    float4 y4;
    y4.x = 0.25f * h4.x + 0.75f * di * fmaf(di, xs.x, ax);
    y4.y = 0.25f * h4.y + 0.75f * di * fmaf(di, xs.y, ay);
    y4.z = 0.25f * h4.z + 0.75f * di * fmaf(di, xs.z, az);
    y4.w = 0.25f * h4.w + 0.75f * di * fmaf(di, xs.w, aw);
    float4 xb;
    if (FIRST) {
      xb = y4;
    } else {
      float4 u4 = ((const float4*)U)[idx];
      xb.x = y4.x - 0.25f * u4.x;
      xb.y = y4.y - 0.25f * u4.y;
      xb.z = y4.z - 0.25f * u4.z;
      xb.w = y4.w - 0.25f * u4.w;
    }
    ((float4*)XB)[idx] = xb;
  }
}

// z <- proj_L21( z + 2*(a*xb[r] - b*xb[c]) ), in place, Z stored fp16.
// Wave = 4 edge rows; rcab is a pure 16B stream here.
template <int FIRST>
__global__ __launch_bounds__(256) void zstep_kernel(
    __half* __restrict__ Z, const float* __restrict__ XB,
    const EInfo* __restrict__ rcab) {
  int w = (int)((blockIdx.x * 256u + threadIdx.x) >> 6);
  int lane = threadIdx.x & 63;
  int g = lane >> 4, l = lane & 15;
  int e = w * 4 + g;
  if (e >= NE) return;
  EInfo ei = rcab[e];
  const float4* X4 = (const float4*)XB;
  uint2* Z2 = (uint2*)Z;
  int zi = e * 16 + l;
  float4 xr = X4[ei.r * 16 + l];
  float4 xc = X4[ei.c * 16 + l];
  float zx, zy, zz, zw;
  if (FIRST) {
    zx = zy = zz = zw = 0.f;   // z0 = 0 (never read poisoned ws)
  } else {
    uint2 zu = Z2[zi];
    float2 f0 = __half22float2(*(const __half2*)&zu.x);
    float2 f1 = __half22float2(*(const __half2*)&zu.y);
    zx = f0.x; zy = f0.y; zz = f1.x; zw = f1.y;
  }
  zx += 2.0f * (ei.a * xr.x - ei.b * xc.x);
  zy += 2.0f * (ei.a * xr.y - ei.b * xc.y);
  zz += 2.0f * (ei.a * xr.z - ei.b * xc.z);
  zw += 2.0f * (ei.a * xr.w - ei.b * xc.w);
  float ss = zx * zx + zy * zy + zz * zz + zw * zw;
  ss += __shfl_xor(ss, 1, 64);
  ss += __shfl_xor(ss, 2, 64);
  ss += __shfl_xor(ss, 4, 64);
  ss += __shfl_xor(ss, 8, 64);   // 16-lane group sum (stays inside group)
  float rn = sqrtf(ss);
  float sc = (rn > LAM) ? (LAM / rn) : 1.0f;
  __half2 o0 = __floats2half2_rn(sc * zx, sc * zy);
  __half2 o1 = __floats2half2_rn(sc * zz, sc * zw);
  uint2 outu;
  outu.x = *(const unsigned*)&o0;
  outu.y = *(const unsigned*)&o1;
  Z2[zi] = outu;
}

// u_new = dis_i * sum_{e incident i} sign_e * z_e ;
// y = XB + 0.25*U_old (reconstructed); Xout = y - 0.25*u_new; U <- u_new.
template <int FIRST, int LAST>
__global__ __launch_bounds__(256) void incT_kernel(
    const __half* __restrict__ Z, const float* __restrict__ XB,
    const float* __restrict__ dis,
    const int* __restrict__ pA, const int2* __restrict__ ents,
    float* __restrict__ U, float* __restrict__ Xout) {
  int w = (int)((blockIdx.x * 256u + threadIdx.x) >> 6);
  if (w >= NN) return;
  int lane = threadIdx.x & 63;
  int g = lane >> 4, l = lane & 15;
  const uint2* Z2 = (const uint2*)Z;
  float ax = 0.f, ay = 0.f, az = 0.f, aw = 0.f;
  int jb = pA[w], je = pA[w + 1];
  int j = jb + g;
  for (; j + 4 < je; j += 8) {
    int raw0 = ents[j].y;
    int raw1 = ents[j + 4].y;
    uint2 zu0 = Z2[(raw0 & 0x7FFFFFFF) * 16 + l];
    uint2 zu1 = Z2[(raw1 & 0x7FFFFFFF) * 16 + l];
    float s0 = (raw0 < 0) ? 1.0f : -1.0f;
    float s1 = (raw1 < 0) ? 1.0f : -1.0f;
    float2 a0 = __half22float2(*(const __half2*)&zu0.x);
    float2 b0 = __half22float2(*(const __half2*)&zu0.y);
    float2 a1 = __half22float2(*(const __half2*)&zu1.x);
    float2 b1 = __half22float2(*(const __half2*)&zu1.y);
    ax = fmaf(s0, a0.x, ax); ay = fmaf(s0, a0.y, ay);
    az = fmaf(s0, b0.x, az); aw = fmaf(s0, b0.y, aw);
    ax = fmaf(s1, a1.x, ax); ay = fmaf(s1, a1.y, ay);
    az = fmaf(s1, b1.x, az); aw = fmaf(s1, b1.y, aw);
  }
  if (j < je) {
    int raw0 = ents[j].y;
    uint2 zu0 = Z2[(raw0 & 0x7FFFFFFF) * 16 + l];
    float s0 = (raw0 < 0) ? 1.0f : -1.0f;
    float2 a0 = __half22float2(*(const __half2*)&zu0.x);
    float2 b0 = __half22float2(*(const __half2*)&zu0.y);
    ax = fmaf(s0, a0.x, ax); ay = fmaf(s0, a0.y, ay);
    az = fmaf(s0, b0.x, az); aw = fmaf(s0, b0.y, aw);
  }
  ax += __shfl_xor(ax, 16, 64); ay += __shfl_xor(ay, 16, 64);
  az += __shfl_xor(az, 16, 64); aw += __shfl_xor(aw, 16, 64);
  ax += __shfl_xor(ax, 32, 64); ay += __shfl_xor(ay, 32, 64);
  az += __shfl_xor(az, 32, 64); aw += __shfl_xor(aw, 32, 64);
  if (g == 0) {
    float di = dis[w];
    int idx = w * 16 + l;
    float4 u;
    u.x = di * ax; u.y = di * ay; u.z = di * az; u.w = di * aw;
    float4 xb = ((const float4*)XB)[idx];
    float4 y4;
    if (FIRST) {
      y4 = xb;  // U_old == 0
    } else {
      float4 uo = ((const float4*)U)[idx];
      y4.x = xb.x + 0.25f * uo.x;
      y4.y = xb.y + 0.25f * uo.y;
      y4.z = xb.z + 0.25f * uo.z;
      y4.w = xb.w + 0.25f * uo.w;
    }
    if (!LAST) ((float4*)U)[idx] = u;  // dead after final step
    float4 o;
    o.x = y4.x - 0.25f * u.x;
    o.y = y4.y - 0.25f * u.y;
    o.z = y4.z - 0.25f * u.z;
    o.w = y4.w - 0.25f * u.w;
    ((float4*)Xout)[idx] = o;
  }
}

// ---------------- launch ----------------

extern "C" void kernel_launch(void* const* d_in, const int* in_sizes, int n_in,
                              void* d_out, int out_size, void* d_ws, size_t ws_size,
                              hipStream_t stream) {
  const float* x  = (const float*)d_in[0];
  const int* esrc = (const int*)d_in[1];
  const int* edst = (const int*)d_in[2];
  float* out = (float*)d_out;

  char* base = (char*)d_ws;
  size_t off = 0;
  auto carve = [&](size_t bytes) -> void* {
    void* p = base + off;
    off += (bytes + 255) & ~(size_t)255;
    return p;
  };
  __half* Z  = (__half*)carve((size_t)NE * 64 * 2);  // 102.4 MB, carry state z
  float* XK  = (float*)carve((size_t)NN * 64 * 4);   // current xk
  float* XB  = (float*)carve((size_t)NN * 64 * 4);   // x_bar
  float* U   = (float*)carve((size_t)NN * 64 * 4);   // incT(z), reused next step
  float* dis = (float*)carve((size_t)NN * 4);
  int* cA = (int*)carve((size_t)NN * 4);
  int* pA = (int*)carve((size_t)(NN + 1) * 4);
  int* uA = (int*)carve((size_t)NN * 4);
  int* bsum = (int*)carve((size_t)SCAN_NB * 4);
  int* boff = (int*)carve((size_t)SCAN_NB * 4);
  int2* ents = (int2*)carve((size_t)2 * NE * 8);     // 12.8 MB incident CSR
  EInfo* rcab = (EInfo*)carve((size_t)NE * 16);      // 12.8 MB per-edge info
  (void)ws_size; (void)in_sizes; (void)n_in; (void)out_size;

  hipMemsetAsync(cA, 0, NN * 4, stream);

  count_kernel<<<(NE + 255) / 256, 256, 0, stream>>>(esrc, edst, cA);
  dis_kernel<<<(NN + 255) / 256, 256, 0, stream>>>(cA, dis);
  rcab_kernel<<<(NE + 255) / 256, 256, 0, stream>>>(esrc, edst, dis, rcab);
  scanA_kernel<<<SCAN_NB, 256, 0, stream>>>(cA, bsum);
  scanB_kernel<<<1, 256, 0, stream>>>(bsum, boff);
  scanC_kernel<<<SCAN_NB, 256, 0, stream>>>(cA, boff, pA, uA);
  scatter_kernel<<<(NE + 255) / 256, 256, 0, stream>>>(esrc, edst, uA, ents);

  const int nodeBlocks = NN * 64 / 256;       // 12500 (one wave/node, exact)
  const int edgeBlocks = (NE / 4) * 64 / 256; // 50000 (wave = 4 edges, exact)

  for (int k = 0; k < KS; ++k) {
    const float* xk = (k == 0) ? x : XK;
    if (k == 0)
      adj_kernel<1><<<nodeBlocks, 256, 0, stream>>>(xk, x, U, dis, pA, ents, XB);
    else
      adj_kernel<0><<<nodeBlocks, 256, 0, stream>>>(xk, x, U, dis, pA, ents, XB);

    if (k == 0)
      zstep_kernel<1><<<edgeBlocks, 256, 0, stream>>>(Z, XB, rcab);
    else
      zstep_kernel<0><<<edgeBlocks, 256, 0, stream>>>(Z, XB, rcab);

    float* xout = (k == KS - 1) ? out : XK;
    if (k == 0)
      incT_kernel<1, 0><<<nodeBlocks, 256, 0, stream>>>(Z, XB, dis, pA, ents, U, xout);
    else if (k == KS - 1)
      incT_kernel<0, 1><<<nodeBlocks, 256, 0, stream>>>(Z, XB, dis, pA, ents, U, xout);
    else
      incT_kernel<0, 0><<<nodeBlocks, 256, 0, stream>>>(Z, XB, dis, pA, ents, U, xout);
  }
}

// Round 5
// 1699.997 us; speedup vs baseline: 1.3047x; 1.1106x over previous
//
#include <hip/hip_runtime.h>
#include <hip/hip_fp16.h>
#include <math.h>

// Problem constants (match reference)
constexpr int NN = 50000;    // nodes
constexpr int NE = 800000;   // undirected edges E0
constexpr int KS = 10;       // iterations
constexpr float LAM = 3.0f;  // lambda

constexpr int SCAN_NB = (NN + 255) / 256;  // 196 scan blocks

// Sorted-edge record. Edges are renumbered so ids are sorted by r=max(s,d).
// Layout pairs (r,a) | (c,b) so adj's r-side can load just the second 8B.
struct __align__(16) EInfo { int r; float a; int c; float b; };

// ---------------- precompute kernels ----------------

__global__ __launch_bounds__(256) void countRC_kernel(
    const int* __restrict__ src, const int* __restrict__ dst,
    int* __restrict__ cR, int* __restrict__ cC) {
  int e = blockIdx.x * 256 + threadIdx.x;
  if (e >= NE) return;
  int s = src[e], d = dst[e];
  int r = s > d ? s : d;
  int c = s > d ? d : s;
  atomicAdd(&cR[r], 1);
  atomicAdd(&cC[c], 1);
}

__global__ __launch_bounds__(256) void dis_kernel(
    const int* __restrict__ cR, const int* __restrict__ cC,
    float* __restrict__ dis) {
  int i = blockIdx.x * 256 + threadIdx.x;
  if (i < NN) dis[i] = 1.0f / sqrtf((float)(cR[i] + cC[i] + 1));
}

// ---- hierarchical exclusive scan: A) block sums, B) scan sums, C) emit ----

__global__ __launch_bounds__(256) void scanA_kernel(
    const int* __restrict__ cnt, int* __restrict__ bsum) {
  __shared__ int sm[256];
  int t = threadIdx.x;
  int i = blockIdx.x * 256 + t;
  int v = (i < NN) ? cnt[i] : 0;
  sm[t] = v;
  __syncthreads();
  for (int off = 128; off > 0; off >>= 1) {
    if (t < off) sm[t] += sm[t + off];
    __syncthreads();
  }
  if (t == 0) bsum[blockIdx.x] = sm[0];
}

__global__ __launch_bounds__(256) void scanB_kernel(
    int* __restrict__ bsum, int* __restrict__ boff) {
  __shared__ int sm[256];
  int t = threadIdx.x;
  int v = (t < SCAN_NB) ? bsum[t] : 0;
  sm[t] = v;
  __syncthreads();
  for (int off = 1; off < 256; off <<= 1) {
    int a = (t >= off) ? sm[t - off] : 0;
    __syncthreads();
    sm[t] += a;
    __syncthreads();
  }
  if (t < SCAN_NB) boff[t] = sm[t] - v;  // exclusive
}

__global__ __launch_bounds__(256) void scanC_kernel(
    const int* __restrict__ cnt, const int* __restrict__ boff,
    int* __restrict__ ptr, int* __restrict__ cur) {
  __shared__ int sm[256];
  int t = threadIdx.x;
  int i = blockIdx.x * 256 + t;
  int v = (i < NN) ? cnt[i] : 0;
  sm[t] = v;
  __syncthreads();
  for (int off = 1; off < 256; off <<= 1) {
    int a = (t >= off) ? sm[t - off] : 0;
    __syncthreads();
    sm[t] += a;
    __syncthreads();
  }
  if (i < NN) {
    int ex = boff[blockIdx.x] + sm[t] - v;  // exclusive prefix
    ptr[i] = ex;
    cur[i] = ex;
    if (i == NN - 1) ptr[NN] = ex + v;
  }
}

// Counting-sort scatter: new edge id p = position in r-sorted order.
// rcab[p] = {r, dis[r], c, dis[c]}; c-side CSR entry (r, p) for node c.
__global__ __launch_bounds__(256) void sortscatter_kernel(
    const int* __restrict__ src, const int* __restrict__ dst,
    const float* __restrict__ dis,
    int* __restrict__ urR, int* __restrict__ uC,
    EInfo* __restrict__ rcab, int2* __restrict__ cEnt) {
  int e = blockIdx.x * 256 + threadIdx.x;
  if (e >= NE) return;
  int s = src[e], d = dst[e];
  int r = s > d ? s : d;
  int c = s > d ? d : s;
  int p = atomicAdd(&urR[r], 1);
  EInfo ei; ei.r = r; ei.a = dis[r]; ei.c = c; ei.b = dis[c];
  rcab[p] = ei;
  int q = atomicAdd(&uC[c], 1);
  cEnt[q] = make_int2(r, p);
}

// ---------------- per-step kernels ----------------
// One wave (64 lanes) per node row; lanes split as 4 groups x 16.
// Group g walks entries jb+g, jb+g+4, ... (x4 unroll on random gathers =>
// 16 independent chains in flight per wave); lane l covers float4 feats
// [4l..4l+3]. Butterfly shfl_xor(16/32) folds the 4 groups.

// y = 0.25*h + 0.75*(D^-1/2 (A+I) D^-1/2) xk ;  XB = x_bar = y - 0.25*U_old
template <int FIRST>
__global__ __launch_bounds__(256) void adj_kernel(
    const float* __restrict__ Xk, const float* __restrict__ H,
    const float* __restrict__ U, const float* __restrict__ dis,
    const int* __restrict__ rPtr, const int* __restrict__ cPtr,
    const int2* __restrict__ cEnt, const EInfo* __restrict__ rcab,
    float* __restrict__ XB) {
  int w = (int)((blockIdx.x * 256u + threadIdx.x) >> 6);
  if (w >= NN) return;
  int lane = threadIdx.x & 63;
  int g = lane >> 4, l = lane & 15;
  const float4* X4 = (const float4*)Xk;
  const uint2* rc2 = (const uint2*)rcab;  // [2*e+1] = (c, dis[c])
  float ax = 0.f, ay = 0.f, az = 0.f, aw = 0.f;
  // r-side: edge id == j, neighbor info streams from sorted rcab
  int jb = rPtr[w], je = rPtr[w + 1];
  int j = jb + g;
  for (; j + 12 < je; j += 16) {
    uint2 v0 = rc2[2 * j + 1];
    uint2 v1 = rc2[2 * (j + 4) + 1];
    uint2 v2 = rc2[2 * (j + 8) + 1];
    uint2 v3 = rc2[2 * (j + 12) + 1];
    float4 x0 = X4[(int)v0.x * 16 + l];
    float4 x1 = X4[(int)v1.x * 16 + l];
    float4 x2 = X4[(int)v2.x * 16 + l];
    float4 x3 = X4[(int)v3.x * 16 + l];
    float w0 = __uint_as_float(v0.y), w1 = __uint_as_float(v1.y);
    float w2 = __uint_as_float(v2.y), w3 = __uint_as_float(v3.y);
    ax = fmaf(w0, x0.x, ax); ay = fmaf(w0, x0.y, ay);
    az = fmaf(w0, x0.z, az); aw = fmaf(w0, x0.w, aw);
    ax = fmaf(w1, x1.x, ax); ay = fmaf(w1, x1.y, ay);
    az = fmaf(w1, x1.z, az); aw = fmaf(w1, x1.w, aw);
    ax = fmaf(w2, x2.x, ax); ay = fmaf(w2, x2.y, ay);
    az = fmaf(w2, x2.z, az); aw = fmaf(w2, x2.w, aw);
    ax = fmaf(w3, x3.x, ax); ay = fmaf(w3, x3.y, ay);
    az = fmaf(w3, x3.z, az); aw = fmaf(w3, x3.w, aw);
  }
  for (; j < je; j += 4) {
    uint2 v0 = rc2[2 * j + 1];
    float4 x0 = X4[(int)v0.x * 16 + l];
    float w0 = __uint_as_float(v0.y);
    ax = fmaf(w0, x0.x, ax); ay = fmaf(w0, x0.y, ay);
    az = fmaf(w0, x0.z, az); aw = fmaf(w0, x0.w, aw);
  }
  // c-side: CSR of (neighbor r, edge id); weight via L2-resident dis[]
  jb = cPtr[w]; je = cPtr[w + 1];
  j = jb + g;
  for (; j + 12 < je; j += 16) {
    int n0 = cEnt[j].x;
    int n1 = cEnt[j + 4].x;
    int n2 = cEnt[j + 8].x;
    int n3 = cEnt[j + 12].x;
    float w0 = dis[n0], w1 = dis[n1], w2 = dis[n2], w3 = dis[n3];
    float4 x0 = X4[n0 * 16 + l];
    float4 x1 = X4[n1 * 16 + l];
    float4 x2 = X4[n2 * 16 + l];
    float4 x3 = X4[n3 * 16 + l];
    ax = fmaf(w0, x0.x, ax); ay = fmaf(w0, x0.y, ay);
    az = fmaf(w0, x0.z, az); aw = fmaf(w0, x0.w, aw);
    ax = fmaf(w1, x1.x, ax); ay = fmaf(w1, x1.y, ay);
    az = fmaf(w1, x1.z, az); aw = fmaf(w1, x1.w, aw);
    ax = fmaf(w2, x2.x, ax); ay = fmaf(w2, x2.y, ay);
    az = fmaf(w2, x2.z, az); aw = fmaf(w2, x2.w, aw);
    ax = fmaf(w3, x3.x, ax); ay = fmaf(w3, x3.y, ay);
    az = fmaf(w3, x3.z, az); aw = fmaf(w3, x3.w, aw);
  }
  for (; j < je; j += 4) {
    int n0 = cEnt[j].x;
    float w0 = dis[n0];
    float4 x0 = X4[n0 * 16 + l];
    ax = fmaf(w0, x0.x, ax); ay = fmaf(w0, x0.y, ay);
    az = fmaf(w0, x0.z, az); aw = fmaf(w0, x0.w, aw);
  }
  ax += __shfl_xor(ax, 16, 64); ay += __shfl_xor(ay, 16, 64);
  az += __shfl_xor(az, 16, 64); aw += __shfl_xor(aw, 16, 64);
  ax += __shfl_xor(ax, 32, 64); ay += __shfl_xor(ay, 32, 64);
  az += __shfl_xor(az, 32, 64); aw += __shfl_xor(aw, 32, 64);
  if (g == 0) {
    float di = dis[w];
    int idx = w * 16 + l;
    float4 xs = X4[idx];
    float4 h4 = ((const float4*)H)[idx];
    float4 y4;
    y4.x = 0.25f * h4.x + 0.75f * di * fmaf(di, xs.x, ax);
    y4.y = 0.25f * h4.y + 0.75f * di * fmaf(di, xs.y, ay);
    y4.z = 0.25f * h4.z + 0.75f * di * fmaf(di, xs.z, az);
    y4.w = 0.25f * h4.w + 0.75f * di * fmaf(di, xs.w, aw);
    float4 xb;
    if (FIRST) {
      xb = y4;
    } else {
      float4 u4 = ((const float4*)U)[idx];
      xb.x = y4.x - 0.25f * u4.x;
      xb.y = y4.y - 0.25f * u4.y;
      xb.z = y4.z - 0.25f * u4.z;
      xb.w = y4.w - 0.25f * u4.w;
    }
    ((float4*)XB)[idx] = xb;
  }
}

// z <- proj_L21( z + 2*(a*xb[r] - b*xb[c]) ), in place, Z stored fp16.
// Wave = 4 consecutive (r-sorted) edges: xr gathers near-sequential.
template <int FIRST>
__global__ __launch_bounds__(256) void zstep_kernel(
    __half* __restrict__ Z, const float* __restrict__ XB,
    const EInfo* __restrict__ rcab) {
  int w = (int)((blockIdx.x * 256u + threadIdx.x) >> 6);
  int lane = threadIdx.x & 63;
  int g = lane >> 4, l = lane & 15;
  int e = w * 4 + g;
  if (e >= NE) return;
  EInfo ei = rcab[e];
  const float4* X4 = (const float4*)XB;
  uint2* Z2 = (uint2*)Z;
  int zi = e * 16 + l;
  float4 xr = X4[ei.r * 16 + l];
  float4 xc = X4[ei.c * 16 + l];
  float zx, zy, zz, zw;
  if (FIRST) {
    zx = zy = zz = zw = 0.f;   // z0 = 0 (never read poisoned ws)
  } else {
    uint2 zu = Z2[zi];
    float2 f0 = __half22float2(*(const __half2*)&zu.x);
    float2 f1 = __half22float2(*(const __half2*)&zu.y);
    zx = f0.x; zy = f0.y; zz = f1.x; zw = f1.y;
  }
  zx += 2.0f * (ei.a * xr.x - ei.b * xc.x);
  zy += 2.0f * (ei.a * xr.y - ei.b * xc.y);
  zz += 2.0f * (ei.a * xr.z - ei.b * xc.z);
  zw += 2.0f * (ei.a * xr.w - ei.b * xc.w);
  float ss = zx * zx + zy * zy + zz * zz + zw * zw;
  ss += __shfl_xor(ss, 1, 64);
  ss += __shfl_xor(ss, 2, 64);
  ss += __shfl_xor(ss, 4, 64);
  ss += __shfl_xor(ss, 8, 64);   // 16-lane group sum (stays inside group)
  float rn = sqrtf(ss);
  float sc = (rn > LAM) ? (LAM / rn) : 1.0f;
  __half2 o0 = __floats2half2_rn(sc * zx, sc * zy);
  __half2 o1 = __floats2half2_rn(sc * zz, sc * zw);
  uint2 outu;
  outu.x = *(const unsigned*)&o0;
  outu.y = *(const unsigned*)&o1;
  Z2[zi] = outu;
}

// u_new = dis_i * (sum_{r-side} z_e - sum_{c-side} z_e);
// y = XB + 0.25*U_old (reconstructed); Xout = y - 0.25*u_new; U <- u_new.
// r-side Z reads are a coalesced stream (edge ids contiguous per node).
template <int FIRST, int LAST>
__global__ __launch_bounds__(256) void incT_kernel(
    const __half* __restrict__ Z, const float* __restrict__ XB,
    const float* __restrict__ dis,
    const int* __restrict__ rPtr, const int* __restrict__ cPtr,
    const int2* __restrict__ cEnt,
    float* __restrict__ U, float* __restrict__ Xout) {
  int w = (int)((blockIdx.x * 256u + threadIdx.x) >> 6);
  if (w >= NN) return;
  int lane = threadIdx.x & 63;
  int g = lane >> 4, l = lane & 15;
  const uint2* Z2 = (const uint2*)Z;
  float ax = 0.f, ay = 0.f, az = 0.f, aw = 0.f;
  // r-side: streaming, sign +
  int jb = rPtr[w], je = rPtr[w + 1];
  int j = jb + g;
  for (; j + 4 < je; j += 8) {
    uint2 zu0 = Z2[j * 16 + l];
    uint2 zu1 = Z2[(j + 4) * 16 + l];
    float2 a0 = __half22float2(*(const __half2*)&zu0.x);
    float2 b0 = __half22float2(*(const __half2*)&zu0.y);
    float2 a1 = __half22float2(*(const __half2*)&zu1.x);
    float2 b1 = __half22float2(*(const __half2*)&zu1.y);
    ax += a0.x + a1.x; ay += a0.y + a1.y;
    az += b0.x + b1.x; aw += b0.y + b1.y;
  }
  if (j < je) {
    uint2 zu0 = Z2[j * 16 + l];
    float2 a0 = __half22float2(*(const __half2*)&zu0.x);
    float2 b0 = __half22float2(*(const __half2*)&zu0.y);
    ax += a0.x; ay += a0.y; az += b0.x; aw += b0.y;
  }
  // c-side: random gather, sign −
  jb = cPtr[w]; je = cPtr[w + 1];
  j = jb + g;
  for (; j + 12 < je; j += 16) {
    int e0 = cEnt[j].y;
    int e1 = cEnt[j + 4].y;
    int e2 = cEnt[j + 8].y;
    int e3 = cEnt[j + 12].y;
    uint2 zu0 = Z2[e0 * 16 + l];
    uint2 zu1 = Z2[e1 * 16 + l];
    uint2 zu2 = Z2[e2 * 16 + l];
    uint2 zu3 = Z2[e3 * 16 + l];
    float2 a0 = __half22float2(*(const __half2*)&zu0.x);
    float2 b0 = __half22float2(*(const __half2*)&zu0.y);
    float2 a1 = __half22float2(*(const __half2*)&zu1.x);
    float2 b1 = __half22float2(*(const __half2*)&zu1.y);
    float2 a2 = __half22float2(*(const __half2*)&zu2.x);
    float2 b2 = __half22float2(*(const __half2*)&zu2.y);
    float2 a3 = __half22float2(*(const __half2*)&zu3.x);
    float2 b3 = __half22float2(*(const __half2*)&zu3.y);
    ax -= a0.x + a1.x + a2.x + a3.x;
    ay -= a0.y + a1.y + a2.y + a3.y;
    az -= b0.x + b1.x + b2.x + b3.x;
    aw -= b0.y + b1.y + b2.y + b3.y;
  }
  for (; j < je; j += 4) {
    int e0 = cEnt[j].y;
    uint2 zu0 = Z2[e0 * 16 + l];
    float2 a0 = __half22float2(*(const __half2*)&zu0.x);
    float2 b0 = __half22float2(*(const __half2*)&zu0.y);
    ax -= a0.x; ay -= a0.y; az -= b0.x; aw -= b0.y;
  }
  ax += __shfl_xor(ax, 16, 64); ay += __shfl_xor(ay, 16, 64);
  az += __shfl_xor(az, 16, 64); aw += __shfl_xor(aw, 16, 64);
  ax += __shfl_xor(ax, 32, 64); ay += __shfl_xor(ay, 32, 64);
  az += __shfl_xor(az, 32, 64); aw += __shfl_xor(aw, 32, 64);
  if (g == 0) {
    float di = dis[w];
    int idx = w * 16 + l;
    float4 u;
    u.x = di * ax; u.y = di * ay; u.z = di * az; u.w = di * aw;
    float4 xb = ((const float4*)XB)[idx];
    float4 y4;
    if (FIRST) {
      y4 = xb;  // U_old == 0
    } else {
      float4 uo = ((const float4*)U)[idx];
      y4.x = xb.x + 0.25f * uo.x;
      y4.y = xb.y + 0.25f * uo.y;
      y4.z = xb.z + 0.25f * uo.z;
      y4.w = xb.w + 0.25f * uo.w;
    }
    if (!LAST) ((float4*)U)[idx] = u;  // dead after final step
    float4 o;
    o.x = y4.x - 0.25f * u.x;
    o.y = y4.y - 0.25f * u.y;
    o.z = y4.z - 0.25f * u.z;
    o.w = y4.w - 0.25f * u.w;
    ((float4*)Xout)[idx] = o;
  }
}

// ---------------- launch ----------------

extern "C" void kernel_launch(void* const* d_in, const int* in_sizes, int n_in,
                              void* d_out, int out_size, void* d_ws, size_t ws_size,
                              hipStream_t stream) {
  const float* x  = (const float*)d_in[0];
  const int* esrc = (const int*)d_in[1];
  const int* edst = (const int*)d_in[2];
  float* out = (float*)d_out;

  char* base = (char*)d_ws;
  size_t off = 0;
  auto carve = [&](size_t bytes) -> void* {
    void* p = base + off;
    off += (bytes + 255) & ~(size_t)255;
    return p;
  };
  __half* Z  = (__half*)carve((size_t)NE * 64 * 2);  // 102.4 MB, carry state z
  float* XK  = (float*)carve((size_t)NN * 64 * 4);   // current xk
  float* XB  = (float*)carve((size_t)NN * 64 * 4);   // x_bar
  float* U   = (float*)carve((size_t)NN * 64 * 4);   // incT(z), reused next step
  float* dis = (float*)carve((size_t)NN * 4);
  int* cR  = (int*)carve((size_t)NN * 4);
  int* cC  = (int*)carve((size_t)NN * 4);
  int* rPtr = (int*)carve((size_t)(NN + 1) * 4);
  int* cPtr = (int*)carve((size_t)(NN + 1) * 4);
  int* urR = (int*)carve((size_t)NN * 4);
  int* uC  = (int*)carve((size_t)NN * 4);
  int* bsum = (int*)carve((size_t)SCAN_NB * 4);
  int* boff = (int*)carve((size_t)SCAN_NB * 4);
  EInfo* rcab = (EInfo*)carve((size_t)NE * 16);      // 12.8 MB sorted edges
  int2* cEnt = (int2*)carve((size_t)NE * 8);         // 6.4 MB c-side CSR
  (void)ws_size; (void)in_sizes; (void)n_in; (void)out_size;

  hipMemsetAsync(cR, 0, NN * 4, stream);
  hipMemsetAsync(cC, 0, NN * 4, stream);

  const int edgeGrid = (NE + 255) / 256;
  countRC_kernel<<<edgeGrid, 256, 0, stream>>>(esrc, edst, cR, cC);
  dis_kernel<<<(NN + 255) / 256, 256, 0, stream>>>(cR, cC, dis);
  scanA_kernel<<<SCAN_NB, 256, 0, stream>>>(cR, bsum);
  scanB_kernel<<<1, 256, 0, stream>>>(bsum, boff);
  scanC_kernel<<<SCAN_NB, 256, 0, stream>>>(cR, boff, rPtr, urR);
  scanA_kernel<<<SCAN_NB, 256, 0, stream>>>(cC, bsum);
  scanB_kernel<<<1, 256, 0, stream>>>(bsum, boff);
  scanC_kernel<<<SCAN_NB, 256, 0, stream>>>(cC, boff, cPtr, uC);
  sortscatter_kernel<<<edgeGrid, 256, 0, stream>>>(esrc, edst, dis, urR, uC,
                                                   rcab, cEnt);

  const int nodeBlocks = NN * 64 / 256;       // 12500 (one wave/node, exact)
  const int edgeBlocks = (NE / 4) * 64 / 256; // 50000 (wave = 4 edges, exact)

  for (int k = 0; k < KS; ++k) {
    const float* xk = (k == 0) ? x : XK;
    if (k == 0)
      adj_kernel<1><<<nodeBlocks, 256, 0, stream>>>(xk, x, U, dis, rPtr, cPtr,
                                                    cEnt, rcab, XB);
    else
      adj_kernel<0><<<nodeBlocks, 256, 0, stream>>>(xk, x, U, dis, rPtr, cPtr,
                                                    cEnt, rcab, XB);

    if (k == 0)
      zstep_kernel<1><<<edgeBlocks, 256, 0, stream>>>(Z, XB, rcab);
    else
      zstep_kernel<0><<<edgeBlocks, 256, 0, stream>>>(Z, XB, rcab);

    float* xout = (k == KS - 1) ? out : XK;
    if (k == 0)
      incT_kernel<1, 0><<<nodeBlocks, 256, 0, stream>>>(Z, XB, dis, rPtr, cPtr,
                                                        cEnt, U, xout);
    else if (k == KS - 1)
      incT_kernel<0, 1><<<nodeBlocks, 256, 0, stream>>>(Z, XB, dis, rPtr, cPtr,
                                                        cEnt, U, xout);
    else
      incT_kernel<0, 0><<<nodeBlocks, 256, 0, stream>>>(Z, XB, dis, rPtr, cPtr,
                                                        cEnt, U, xout);
  }
}

// Round 6
// 1676.189 us; speedup vs baseline: 1.3232x; 1.0142x over previous
//
#include <hip/hip_runtime.h>
#include <hip/hip_fp16.h>
#include <math.h>

// Problem constants (match reference)
constexpr int NN = 50000;    // nodes
constexpr int NE = 800000;   // undirected edges E0
constexpr int KS = 10;       // iterations
constexpr float LAM = 3.0f;  // lambda

constexpr int SCAN_NB = (NN + 255) / 256;  // 196 scan blocks

// Sorted-edge record. Edges are renumbered so ids are sorted by r=max(s,d).
struct __align__(16) EInfo { int r; float a; int c; float b; };

// ---------------- precompute kernels ----------------

__global__ __launch_bounds__(256) void countRC_kernel(
    const int* __restrict__ src, const int* __restrict__ dst,
    int* __restrict__ cR, int* __restrict__ cC) {
  int e = blockIdx.x * 256 + threadIdx.x;
  if (e >= NE) return;
  int s = src[e], d = dst[e];
  int r = s > d ? s : d;
  int c = s > d ? d : s;
  atomicAdd(&cR[r], 1);
  atomicAdd(&cC[c], 1);
}

__global__ __launch_bounds__(256) void dis_kernel(
    const int* __restrict__ cR, const int* __restrict__ cC,
    float* __restrict__ dis) {
  int i = blockIdx.x * 256 + threadIdx.x;
  if (i < NN) dis[i] = 1.0f / sqrtf((float)(cR[i] + cC[i] + 1));
}

// ---- hierarchical exclusive scan: A) block sums, B) scan sums, C) emit ----

__global__ __launch_bounds__(256) void scanA_kernel(
    const int* __restrict__ cnt, int* __restrict__ bsum) {
  __shared__ int sm[256];
  int t = threadIdx.x;
  int i = blockIdx.x * 256 + t;
  int v = (i < NN) ? cnt[i] : 0;
  sm[t] = v;
  __syncthreads();
  for (int off = 128; off > 0; off >>= 1) {
    if (t < off) sm[t] += sm[t + off];
    __syncthreads();
  }
  if (t == 0) bsum[blockIdx.x] = sm[0];
}

__global__ __launch_bounds__(256) void scanB_kernel(
    int* __restrict__ bsum, int* __restrict__ boff) {
  __shared__ int sm[256];
  int t = threadIdx.x;
  int v = (t < SCAN_NB) ? bsum[t] : 0;
  sm[t] = v;
  __syncthreads();
  for (int off = 1; off < 256; off <<= 1) {
    int a = (t >= off) ? sm[t - off] : 0;
    __syncthreads();
    sm[t] += a;
    __syncthreads();
  }
  if (t < SCAN_NB) boff[t] = sm[t] - v;  // exclusive
}

__global__ __launch_bounds__(256) void scanC_kernel(
    const int* __restrict__ cnt, const int* __restrict__ boff,
    int* __restrict__ ptr, int* __restrict__ cur) {
  __shared__ int sm[256];
  int t = threadIdx.x;
  int i = blockIdx.x * 256 + t;
  int v = (i < NN) ? cnt[i] : 0;
  sm[t] = v;
  __syncthreads();
  for (int off = 1; off < 256; off <<= 1) {
    int a = (t >= off) ? sm[t - off] : 0;
    __syncthreads();
    sm[t] += a;
    __syncthreads();
  }
  if (i < NN) {
    int ex = boff[blockIdx.x] + sm[t] - v;  // exclusive prefix
    ptr[i] = ex;
    cur[i] = ex;
    if (i == NN - 1) ptr[NN] = ex + v;
  }
}

// Counting-sort scatter: new edge id p = position in r-sorted order.
// rcab[p] = {r, dis[r], c, dis[c]}; c-side CSR entry (r, p) for node c.
__global__ __launch_bounds__(256) void sortscatter_kernel(
    const int* __restrict__ src, const int* __restrict__ dst,
    const float* __restrict__ dis,
    int* __restrict__ urR, int* __restrict__ uC,
    EInfo* __restrict__ rcab, int2* __restrict__ cEnt) {
  int e = blockIdx.x * 256 + threadIdx.x;
  if (e >= NE) return;
  int s = src[e], d = dst[e];
  int r = s > d ? s : d;
  int c = s > d ? d : s;
  int p = atomicAdd(&urR[r], 1);
  EInfo ei; ei.r = r; ei.a = dis[r]; ei.c = c; ei.b = dis[c];
  rcab[p] = ei;
  int q = atomicAdd(&uC[c], 1);
  cEnt[q] = make_int2(r, p);
}

// ---------------- per-step kernels ----------------
// One wave (64 lanes) per node row; lanes split as 4 groups x 16.
// Each node's r-side (streaming) and c-side (CSR) lists are walked as ONE
// concatenated list of length total=lenR+lenC; group g covers t=g,g+4,...
// branch-free (clamped metadata loads + selects), x4 unrolled => 16
// independent gather chains per wave, balanced across r/c skew.
// Lane l covers float4 feats [4l..4l+3]; shfl_xor(16/32) folds groups.

// y = 0.25*h + 0.75*(D^-1/2 (A+I) D^-1/2) xk ;  XB = x_bar = y - 0.25*U_old
template <int FIRST>
__global__ __launch_bounds__(256) void adj_kernel(
    const float* __restrict__ Xk, const float* __restrict__ H,
    const float* __restrict__ U, const float* __restrict__ dis,
    const int* __restrict__ rPtr, const int* __restrict__ cPtr,
    const int2* __restrict__ cEnt, const EInfo* __restrict__ rcab,
    float* __restrict__ XB) {
  int w = (int)((blockIdx.x * 256u + threadIdx.x) >> 6);
  if (w >= NN) return;
  int lane = threadIdx.x & 63;
  int g = lane >> 4, l = lane & 15;
  const float4* X4 = (const float4*)Xk;
  const uint2* rc2 = (const uint2*)rcab;  // [2*e+1] = (c, dis[c])
  int rb = rPtr[w], lenR = rPtr[w + 1] - rb;
  int cb = cPtr[w], lenC = cPtr[w + 1] - cb;
  int total = lenR + lenC;
  int lr1 = lenR > 0 ? lenR - 1 : 0;
  int lc1 = lenC > 0 ? lenC - 1 : 0;
  float ax = 0.f, ay = 0.f, az = 0.f, aw = 0.f;

#define ADJ_FETCH(T, NB, WT)                                         \
  {                                                                  \
    int tr = (T) < lr1 ? (T) : lr1;                                  \
    int tc = (T) - lenR; tc = tc > 0 ? tc : 0; tc = tc < lc1 ? tc : lc1; \
    uint2 rc = rc2[2 * (rb + tr) + 1];                               \
    int2 ce = cEnt[cb + tc];                                         \
    bool isR = (T) < lenR;                                           \
    NB = isR ? (int)rc.x : ce.x;                                     \
    WT = isR ? __uint_as_float(rc.y) : dis[ce.x];                    \
  }

  int t = g;
  for (; t + 12 < total; t += 16) {
    int n0, n1, n2, n3; float w0, w1, w2, w3;
    ADJ_FETCH(t, n0, w0);
    ADJ_FETCH(t + 4, n1, w1);
    ADJ_FETCH(t + 8, n2, w2);
    ADJ_FETCH(t + 12, n3, w3);
    float4 x0 = X4[n0 * 16 + l];
    float4 x1 = X4[n1 * 16 + l];
    float4 x2 = X4[n2 * 16 + l];
    float4 x3 = X4[n3 * 16 + l];
    ax = fmaf(w0, x0.x, ax); ay = fmaf(w0, x0.y, ay);
    az = fmaf(w0, x0.z, az); aw = fmaf(w0, x0.w, aw);
    ax = fmaf(w1, x1.x, ax); ay = fmaf(w1, x1.y, ay);
    az = fmaf(w1, x1.z, az); aw = fmaf(w1, x1.w, aw);
    ax = fmaf(w2, x2.x, ax); ay = fmaf(w2, x2.y, ay);
    az = fmaf(w2, x2.z, az); aw = fmaf(w2, x2.w, aw);
    ax = fmaf(w3, x3.x, ax); ay = fmaf(w3, x3.y, ay);
    az = fmaf(w3, x3.z, az); aw = fmaf(w3, x3.w, aw);
  }
  for (; t < total; t += 4) {
    int n0; float w0;
    ADJ_FETCH(t, n0, w0);
    float4 x0 = X4[n0 * 16 + l];
    ax = fmaf(w0, x0.x, ax); ay = fmaf(w0, x0.y, ay);
    az = fmaf(w0, x0.z, az); aw = fmaf(w0, x0.w, aw);
  }
#undef ADJ_FETCH

  ax += __shfl_xor(ax, 16, 64); ay += __shfl_xor(ay, 16, 64);
  az += __shfl_xor(az, 16, 64); aw += __shfl_xor(aw, 16, 64);
  ax += __shfl_xor(ax, 32, 64); ay += __shfl_xor(ay, 32, 64);
  az += __shfl_xor(az, 32, 64); aw += __shfl_xor(aw, 32, 64);
  if (g == 0) {
    float di = dis[w];
    int idx = w * 16 + l;
    float4 xs = X4[idx];
    float4 h4 = ((const float4*)H)[idx];
    float4 y4;
    y4.x = 0.25f * h4.x + 0.75f * di * fmaf(di, xs.x, ax);
    y4.y = 0.25f * h4.y + 0.75f * di * fmaf(di, xs.y, ay);
    y4.z = 0.25f * h4.z + 0.75f * di * fmaf(di, xs.z, az);
    y4.w = 0.25f * h4.w + 0.75f * di * fmaf(di, xs.w, aw);
    float4 xb;
    if (FIRST) {
      xb = y4;
    } else {
      float4 u4 = ((const float4*)U)[idx];
      xb.x = y4.x - 0.25f * u4.x;
      xb.y = y4.y - 0.25f * u4.y;
      xb.z = y4.z - 0.25f * u4.z;
      xb.w = y4.w - 0.25f * u4.w;
    }
    ((float4*)XB)[idx] = xb;
  }
}

// z <- proj_L21( z + 2*(a*xb[r] - b*xb[c]) ), in place, Z stored fp16.
// Wave = 8 consecutive (r-sorted) edges, 2 per 16-lane group (doubled MLP).
template <int FIRST>
__global__ __launch_bounds__(256) void zstep_kernel(
    __half* __restrict__ Z, const float* __restrict__ XB,
    const EInfo* __restrict__ rcab) {
  int w = (int)((blockIdx.x * 256u + threadIdx.x) >> 6);
  int base = w * 8;
  if (base >= NE) return;
  int lane = threadIdx.x & 63;
  int g = lane >> 4, l = lane & 15;
  int e0 = base + g, e1 = base + g + 4;
  EInfo ei0 = rcab[e0];
  EInfo ei1 = rcab[e1];
  const float4* X4 = (const float4*)XB;
  uint2* Z2 = (uint2*)Z;
  int zi0 = e0 * 16 + l, zi1 = e1 * 16 + l;
  float4 xr0 = X4[ei0.r * 16 + l];
  float4 xc0 = X4[ei0.c * 16 + l];
  float4 xr1 = X4[ei1.r * 16 + l];
  float4 xc1 = X4[ei1.c * 16 + l];
  float zx0, zy0, zz0, zw0, zx1, zy1, zz1, zw1;
  if (FIRST) {
    zx0 = zy0 = zz0 = zw0 = 0.f;
    zx1 = zy1 = zz1 = zw1 = 0.f;
  } else {
    uint2 zu0 = Z2[zi0];
    uint2 zu1 = Z2[zi1];
    float2 f0 = __half22float2(*(const __half2*)&zu0.x);
    float2 f1 = __half22float2(*(const __half2*)&zu0.y);
    zx0 = f0.x; zy0 = f0.y; zz0 = f1.x; zw0 = f1.y;
    f0 = __half22float2(*(const __half2*)&zu1.x);
    f1 = __half22float2(*(const __half2*)&zu1.y);
    zx1 = f0.x; zy1 = f0.y; zz1 = f1.x; zw1 = f1.y;
  }
  zx0 += 2.0f * (ei0.a * xr0.x - ei0.b * xc0.x);
  zy0 += 2.0f * (ei0.a * xr0.y - ei0.b * xc0.y);
  zz0 += 2.0f * (ei0.a * xr0.z - ei0.b * xc0.z);
  zw0 += 2.0f * (ei0.a * xr0.w - ei0.b * xc0.w);
  zx1 += 2.0f * (ei1.a * xr1.x - ei1.b * xc1.x);
  zy1 += 2.0f * (ei1.a * xr1.y - ei1.b * xc1.y);
  zz1 += 2.0f * (ei1.a * xr1.z - ei1.b * xc1.z);
  zw1 += 2.0f * (ei1.a * xr1.w - ei1.b * xc1.w);
  float s0 = zx0 * zx0 + zy0 * zy0 + zz0 * zz0 + zw0 * zw0;
  float s1 = zx1 * zx1 + zy1 * zy1 + zz1 * zz1 + zw1 * zw1;
  s0 += __shfl_xor(s0, 1, 64); s1 += __shfl_xor(s1, 1, 64);
  s0 += __shfl_xor(s0, 2, 64); s1 += __shfl_xor(s1, 2, 64);
  s0 += __shfl_xor(s0, 4, 64); s1 += __shfl_xor(s1, 4, 64);
  s0 += __shfl_xor(s0, 8, 64); s1 += __shfl_xor(s1, 8, 64);
  float rn0 = sqrtf(s0), rn1 = sqrtf(s1);
  float sc0 = (rn0 > LAM) ? (LAM / rn0) : 1.0f;
  float sc1 = (rn1 > LAM) ? (LAM / rn1) : 1.0f;
  __half2 a0 = __floats2half2_rn(sc0 * zx0, sc0 * zy0);
  __half2 b0 = __floats2half2_rn(sc0 * zz0, sc0 * zw0);
  __half2 a1 = __floats2half2_rn(sc1 * zx1, sc1 * zy1);
  __half2 b1 = __floats2half2_rn(sc1 * zz1, sc1 * zw1);
  uint2 o0, o1;
  o0.x = *(const unsigned*)&a0; o0.y = *(const unsigned*)&b0;
  o1.x = *(const unsigned*)&a1; o1.y = *(const unsigned*)&b1;
  Z2[zi0] = o0;
  Z2[zi1] = o1;
}

// u_new = dis_i * (sum_{r-side} z_e - sum_{c-side} z_e);  unified walk:
// t<lenR -> edge id rb+t (no metadata, + sign); else cEnt (gather, - sign).
// y = XB + 0.25*U_old (reconstructed); Xout = y - 0.25*u_new; U <- u_new.
template <int FIRST, int LAST>
__global__ __launch_bounds__(256) void incT_kernel(
    const __half* __restrict__ Z, const float* __restrict__ XB,
    const float* __restrict__ dis,
    const int* __restrict__ rPtr, const int* __restrict__ cPtr,
    const int2* __restrict__ cEnt,
    float* __restrict__ U, float* __restrict__ Xout) {
  int w = (int)((blockIdx.x * 256u + threadIdx.x) >> 6);
  if (w >= NN) return;
  int lane = threadIdx.x & 63;
  int g = lane >> 4, l = lane & 15;
  const uint2* Z2 = (const uint2*)Z;
  int rb = rPtr[w], lenR = rPtr[w + 1] - rb;
  int cb = cPtr[w], lenC = cPtr[w + 1] - cb;
  int total = lenR + lenC;
  int lc1 = lenC > 0 ? lenC - 1 : 0;
  float ax = 0.f, ay = 0.f, az = 0.f, aw = 0.f;

#define INCT_FETCH(T, E, SG)                                         \
  {                                                                  \
    int tc = (T) - lenR; tc = tc > 0 ? tc : 0; tc = tc < lc1 ? tc : lc1; \
    int2 ce = cEnt[cb + tc];                                         \
    bool isR = (T) < lenR;                                           \
    E = isR ? (rb + (T)) : ce.y;                                     \
    SG = isR ? 1.0f : -1.0f;                                         \
  }

  int t = g;
  for (; t + 12 < total; t += 16) {
    int e0, e1, e2, e3; float s0, s1, s2, s3;
    INCT_FETCH(t, e0, s0);
    INCT_FETCH(t + 4, e1, s1);
    INCT_FETCH(t + 8, e2, s2);
    INCT_FETCH(t + 12, e3, s3);
    uint2 zu0 = Z2[e0 * 16 + l];
    uint2 zu1 = Z2[e1 * 16 + l];
    uint2 zu2 = Z2[e2 * 16 + l];
    uint2 zu3 = Z2[e3 * 16 + l];
    float2 a0 = __half22float2(*(const __half2*)&zu0.x);
    float2 b0 = __half22float2(*(const __half2*)&zu0.y);
    float2 a1 = __half22float2(*(const __half2*)&zu1.x);
    float2 b1 = __half22float2(*(const __half2*)&zu1.y);
    float2 a2 = __half22float2(*(const __half2*)&zu2.x);
    float2 b2 = __half22float2(*(const __half2*)&zu2.y);
    float2 a3 = __half22float2(*(const __half2*)&zu3.x);
    float2 b3 = __half22float2(*(const __half2*)&zu3.y);
    ax = fmaf(s0, a0.x, ax); ay = fmaf(s0, a0.y, ay);
    az = fmaf(s0, b0.x, az); aw = fmaf(s0, b0.y, aw);
    ax = fmaf(s1, a1.x, ax); ay = fmaf(s1, a1.y, ay);
    az = fmaf(s1, b1.x, az); aw = fmaf(s1, b1.y, aw);
    ax = fmaf(s2, a2.x, ax); ay = fmaf(s2, a2.y, ay);
    az = fmaf(s2, b2.x, az); aw = fmaf(s2, b2.y, aw);
    ax = fmaf(s3, a3.x, ax); ay = fmaf(s3, a3.y, ay);
    az = fmaf(s3, b3.x, az); aw = fmaf(s3, b3.y, aw);
  }
  for (; t < total; t += 4) {
    int e0; float s0;
    INCT_FETCH(t, e0, s0);
    uint2 zu0 = Z2[e0 * 16 + l];
    float2 a0 = __half22float2(*(const __half2*)&zu0.x);
    float2 b0 = __half22float2(*(const __half2*)&zu0.y);
    ax = fmaf(s0, a0.x, ax); ay = fmaf(s0, a0.y, ay);
    az = fmaf(s0, b0.x, az); aw = fmaf(s0, b0.y, aw);
  }
#undef INCT_FETCH

  ax += __shfl_xor(ax, 16, 64); ay += __shfl_xor(ay, 16, 64);
  az += __shfl_xor(az, 16, 64); aw += __shfl_xor(aw, 16, 64);
  ax += __shfl_xor(ax, 32, 64); ay += __shfl_xor(ay, 32, 64);
  az += __shfl_xor(az, 32, 64); aw += __shfl_xor(aw, 32, 64);
  if (g == 0) {
    float di = dis[w];
    int idx = w * 16 + l;
    float4 u;
    u.x = di * ax; u.y = di * ay; u.z = di * az; u.w = di * aw;
    float4 xb = ((const float4*)XB)[idx];
    float4 y4;
    if (FIRST) {
      y4 = xb;  // U_old == 0
    } else {
      float4 uo = ((const float4*)U)[idx];
      y4.x = xb.x + 0.25f * uo.x;
      y4.y = xb.y + 0.25f * uo.y;
      y4.z = xb.z + 0.25f * uo.z;
      y4.w = xb.w + 0.25f * uo.w;
    }
    if (!LAST) ((float4*)U)[idx] = u;  // dead after final step
    float4 o;
    o.x = y4.x - 0.25f * u.x;
    o.y = y4.y - 0.25f * u.y;
    o.z = y4.z - 0.25f * u.z;
    o.w = y4.w - 0.25f * u.w;
    ((float4*)Xout)[idx] = o;
  }
}

// ---------------- launch ----------------

extern "C" void kernel_launch(void* const* d_in, const int* in_sizes, int n_in,
                              void* d_out, int out_size, void* d_ws, size_t ws_size,
                              hipStream_t stream) {
  const float* x  = (const float*)d_in[0];
  const int* esrc = (const int*)d_in[1];
  const int* edst = (const int*)d_in[2];
  float* out = (float*)d_out;

  char* base = (char*)d_ws;
  size_t off = 0;
  auto carve = [&](size_t bytes) -> void* {
    void* p = base + off;
    off += (bytes + 255) & ~(size_t)255;
    return p;
  };
  __half* Z  = (__half*)carve((size_t)NE * 64 * 2);  // 102.4 MB, carry state z
  float* XK  = (float*)carve((size_t)NN * 64 * 4);   // current xk
  float* XB  = (float*)carve((size_t)NN * 64 * 4);   // x_bar
  float* U   = (float*)carve((size_t)NN * 64 * 4);   // incT(z), reused next step
  float* dis = (float*)carve((size_t)NN * 4);
  int* cR  = (int*)carve((size_t)NN * 4);
  int* cC  = (int*)carve((size_t)NN * 4);
  int* rPtr = (int*)carve((size_t)(NN + 1) * 4);
  int* cPtr = (int*)carve((size_t)(NN + 1) * 4);
  int* urR = (int*)carve((size_t)NN * 4);
  int* uC  = (int*)carve((size_t)NN * 4);
  int* bsum = (int*)carve((size_t)SCAN_NB * 4);
  int* boff = (int*)carve((size_t)SCAN_NB * 4);
  EInfo* rcab = (EInfo*)carve((size_t)NE * 16);      // 12.8 MB sorted edges
  int2* cEnt = (int2*)carve((size_t)NE * 8);         // 6.4 MB c-side CSR
  (void)ws_size; (void)in_sizes; (void)n_in; (void)out_size;

  hipMemsetAsync(cR, 0, NN * 4, stream);
  hipMemsetAsync(cC, 0, NN * 4, stream);

  const int edgeGrid = (NE + 255) / 256;
  countRC_kernel<<<edgeGrid, 256, 0, stream>>>(esrc, edst, cR, cC);
  dis_kernel<<<(NN + 255) / 256, 256, 0, stream>>>(cR, cC, dis);
  scanA_kernel<<<SCAN_NB, 256, 0, stream>>>(cR, bsum);
  scanB_kernel<<<1, 256, 0, stream>>>(bsum, boff);
  scanC_kernel<<<SCAN_NB, 256, 0, stream>>>(cR, boff, rPtr, urR);
  scanA_kernel<<<SCAN_NB, 256, 0, stream>>>(cC, bsum);
  scanB_kernel<<<1, 256, 0, stream>>>(bsum, boff);
  scanC_kernel<<<SCAN_NB, 256, 0, stream>>>(cC, boff, cPtr, uC);
  sortscatter_kernel<<<edgeGrid, 256, 0, stream>>>(esrc, edst, dis, urR, uC,
                                                   rcab, cEnt);

  const int nodeBlocks = NN * 64 / 256;       // 12500 (one wave/node, exact)
  const int edgeBlocks = (NE / 8) * 64 / 256; // 25000 (wave = 8 edges, exact)

  for (int k = 0; k < KS; ++k) {
    const float* xk = (k == 0) ? x : XK;
    if (k == 0)
      adj_kernel<1><<<nodeBlocks, 256, 0, stream>>>(xk, x, U, dis, rPtr, cPtr,
                                                    cEnt, rcab, XB);
    else
      adj_kernel<0><<<nodeBlocks, 256, 0, stream>>>(xk, x, U, dis, rPtr, cPtr,
                                                    cEnt, rcab, XB);

    if (k == 0)
      zstep_kernel<1><<<edgeBlocks, 256, 0, stream>>>(Z, XB, rcab);
    else
      zstep_kernel<0><<<edgeBlocks, 256, 0, stream>>>(Z, XB, rcab);

    float* xout = (k == KS - 1) ? out : XK;
    if (k == 0)
      incT_kernel<1, 0><<<nodeBlocks, 256, 0, stream>>>(Z, XB, dis, rPtr, cPtr,
                                                        cEnt, U, xout);
    else if (k == KS - 1)
      incT_kernel<0, 1><<<nodeBlocks, 256, 0, stream>>>(Z, XB, dis, rPtr, cPtr,
                                                        cEnt, U, xout);
    else
      incT_kernel<0, 0><<<nodeBlocks, 256, 0, stream>>>(Z, XB, dis, rPtr, cPtr,
                                                        cEnt, U, xout);
  }
}

// Round 7
// 1426.576 us; speedup vs baseline: 1.5548x; 1.1750x over previous
//
#include <hip/hip_runtime.h>
#include <hip/hip_fp16.h>
#include <math.h>

// Problem constants (match reference)
constexpr int NN = 50000;    // nodes
constexpr int NE = 800000;   // undirected edges E0
constexpr int KS = 10;       // iterations
constexpr float LAM = 3.0f;  // lambda

constexpr int SCAN_NB = (NN + 255) / 256;  // 196 scan blocks

// Sorted-edge record. Edges are renumbered so ids are sorted by r=max(s,d).
struct __align__(16) EInfo { int r; float a; int c; float b; };

// ---------------- precompute kernels ----------------

__global__ __launch_bounds__(256) void countRC_kernel(
    const int* __restrict__ src, const int* __restrict__ dst,
    int* __restrict__ cR, int* __restrict__ cC) {
  int e = blockIdx.x * 256 + threadIdx.x;
  if (e >= NE) return;
  int s = src[e], d = dst[e];
  int r = s > d ? s : d;
  int c = s > d ? d : s;
  atomicAdd(&cR[r], 1);
  atomicAdd(&cC[c], 1);
}

__global__ __launch_bounds__(256) void dis_kernel(
    const int* __restrict__ cR, const int* __restrict__ cC,
    float* __restrict__ dis) {
  int i = blockIdx.x * 256 + threadIdx.x;
  if (i < NN) dis[i] = 1.0f / sqrtf((float)(cR[i] + cC[i] + 1));
}

// fp16 shadow of a [NN x 64] fp32 array (vectorized 4 floats/thread)
__global__ __launch_bounds__(256) void half_copy_kernel(
    const float* __restrict__ X, __half* __restrict__ XH) {
  int i = blockIdx.x * 256 + threadIdx.x;
  if (i >= NN * 16) return;
  float4 v = ((const float4*)X)[i];
  __half2 h0 = __floats2half2_rn(v.x, v.y);
  __half2 h1 = __floats2half2_rn(v.z, v.w);
  uint2 o;
  o.x = *(const unsigned*)&h0;
  o.y = *(const unsigned*)&h1;
  ((uint2*)XH)[i] = o;
}

// ---- hierarchical exclusive scan: A) block sums, B) scan sums, C) emit ----

__global__ __launch_bounds__(256) void scanA_kernel(
    const int* __restrict__ cnt, int* __restrict__ bsum) {
  __shared__ int sm[256];
  int t = threadIdx.x;
  int i = blockIdx.x * 256 + t;
  int v = (i < NN) ? cnt[i] : 0;
  sm[t] = v;
  __syncthreads();
  for (int off = 128; off > 0; off >>= 1) {
    if (t < off) sm[t] += sm[t + off];
    __syncthreads();
  }
  if (t == 0) bsum[blockIdx.x] = sm[0];
}

__global__ __launch_bounds__(256) void scanB_kernel(
    int* __restrict__ bsum, int* __restrict__ boff) {
  __shared__ int sm[256];
  int t = threadIdx.x;
  int v = (t < SCAN_NB) ? bsum[t] : 0;
  sm[t] = v;
  __syncthreads();
  for (int off = 1; off < 256; off <<= 1) {
    int a = (t >= off) ? sm[t - off] : 0;
    __syncthreads();
    sm[t] += a;
    __syncthreads();
  }
  if (t < SCAN_NB) boff[t] = sm[t] - v;  // exclusive
}

__global__ __launch_bounds__(256) void scanC_kernel(
    const int* __restrict__ cnt, const int* __restrict__ boff,
    int* __restrict__ ptr, int* __restrict__ cur) {
  __shared__ int sm[256];
  int t = threadIdx.x;
  int i = blockIdx.x * 256 + t;
  int v = (i < NN) ? cnt[i] : 0;
  sm[t] = v;
  __syncthreads();
  for (int off = 1; off < 256; off <<= 1) {
    int a = (t >= off) ? sm[t - off] : 0;
    __syncthreads();
    sm[t] += a;
    __syncthreads();
  }
  if (i < NN) {
    int ex = boff[blockIdx.x] + sm[t] - v;  // exclusive prefix
    ptr[i] = ex;
    cur[i] = ex;
    if (i == NN - 1) ptr[NN] = ex + v;
  }
}

// Counting-sort scatter: new edge id p = position in r-sorted order.
// rcab[p] = {r, dis[r], c, dis[c]}; c-side CSR entry (r, p) for node c.
__global__ __launch_bounds__(256) void sortscatter_kernel(
    const int* __restrict__ src, const int* __restrict__ dst,
    const float* __restrict__ dis,
    int* __restrict__ urR, int* __restrict__ uC,
    EInfo* __restrict__ rcab, int2* __restrict__ cEnt) {
  int e = blockIdx.x * 256 + threadIdx.x;
  if (e >= NE) return;
  int s = src[e], d = dst[e];
  int r = s > d ? s : d;
  int c = s > d ? d : s;
  int p = atomicAdd(&urR[r], 1);
  EInfo ei; ei.r = r; ei.a = dis[r]; ei.c = c; ei.b = dis[c];
  rcab[p] = ei;
  int q = atomicAdd(&uC[c], 1);
  cEnt[q] = make_int2(r, p);
}

// ---------------- per-step kernels ----------------
// One wave (64 lanes) per node row; lanes split as 4 groups x 16.
// Unified concatenated r-side/c-side walk (branch-free), x4 unrolled.
// Gathered features come from fp16 SHADOW arrays (8B/lane, half the L3
// bytes of fp32); streaming/epilogue reads stay fp32.

// y = 0.25*h + 0.75*(D^-1/2 (A+I) D^-1/2) xk ;  XB = x_bar = y - 0.25*U_old
// Gathers from XH (fp16 shadow of xk); writes XB (fp32) + XBh (fp16).
template <int FIRST>
__global__ __launch_bounds__(256) void adj_kernel(
    const float* __restrict__ Xk, const __half* __restrict__ XH,
    const float* __restrict__ H, const float* __restrict__ U,
    const float* __restrict__ dis,
    const int* __restrict__ rPtr, const int* __restrict__ cPtr,
    const int2* __restrict__ cEnt, const EInfo* __restrict__ rcab,
    float* __restrict__ XB, __half* __restrict__ XBh) {
  int w = (int)((blockIdx.x * 256u + threadIdx.x) >> 6);
  if (w >= NN) return;
  int lane = threadIdx.x & 63;
  int g = lane >> 4, l = lane & 15;
  const uint2* XH2 = (const uint2*)XH;
  const uint2* rc2 = (const uint2*)rcab;  // [2*e+1] = (c, dis[c])
  int rb = rPtr[w], lenR = rPtr[w + 1] - rb;
  int cb = cPtr[w], lenC = cPtr[w + 1] - cb;
  int total = lenR + lenC;
  int lr1 = lenR > 0 ? lenR - 1 : 0;
  int lc1 = lenC > 0 ? lenC - 1 : 0;
  float ax = 0.f, ay = 0.f, az = 0.f, aw = 0.f;

#define ADJ_FETCH(T, NB, WT)                                         \
  {                                                                  \
    int tr = (T) < lr1 ? (T) : lr1;                                  \
    int tc = (T) - lenR; tc = tc > 0 ? tc : 0; tc = tc < lc1 ? tc : lc1; \
    uint2 rc = rc2[2 * (rb + tr) + 1];                               \
    int2 ce = cEnt[cb + tc];                                         \
    bool isR = (T) < lenR;                                           \
    NB = isR ? (int)rc.x : ce.x;                                     \
    WT = isR ? __uint_as_float(rc.y) : dis[ce.x];                    \
  }
#define ADJ_ACC(XV, W)                                               \
  {                                                                  \
    float2 p = __half22float2(*(const __half2*)&XV.x);               \
    float2 q = __half22float2(*(const __half2*)&XV.y);               \
    ax = fmaf(W, p.x, ax); ay = fmaf(W, p.y, ay);                    \
    az = fmaf(W, q.x, az); aw = fmaf(W, q.y, aw);                    \
  }

  int t = g;
  for (; t + 12 < total; t += 16) {
    int n0, n1, n2, n3; float w0, w1, w2, w3;
    ADJ_FETCH(t, n0, w0);
    ADJ_FETCH(t + 4, n1, w1);
    ADJ_FETCH(t + 8, n2, w2);
    ADJ_FETCH(t + 12, n3, w3);
    uint2 x0 = XH2[n0 * 16 + l];
    uint2 x1 = XH2[n1 * 16 + l];
    uint2 x2 = XH2[n2 * 16 + l];
    uint2 x3 = XH2[n3 * 16 + l];
    ADJ_ACC(x0, w0);
    ADJ_ACC(x1, w1);
    ADJ_ACC(x2, w2);
    ADJ_ACC(x3, w3);
  }
  for (; t < total; t += 4) {
    int n0; float w0;
    ADJ_FETCH(t, n0, w0);
    uint2 x0 = XH2[n0 * 16 + l];
    ADJ_ACC(x0, w0);
  }
#undef ADJ_FETCH
#undef ADJ_ACC

  ax += __shfl_xor(ax, 16, 64); ay += __shfl_xor(ay, 16, 64);
  az += __shfl_xor(az, 16, 64); aw += __shfl_xor(aw, 16, 64);
  ax += __shfl_xor(ax, 32, 64); ay += __shfl_xor(ay, 32, 64);
  az += __shfl_xor(az, 32, 64); aw += __shfl_xor(aw, 32, 64);
  if (g == 0) {
    float di = dis[w];
    int idx = w * 16 + l;
    float4 xs = ((const float4*)Xk)[idx];  // self term from fp32 master
    float4 h4 = ((const float4*)H)[idx];
    float4 y4;
    y4.x = 0.25f * h4.x + 0.75f * di * fmaf(di, xs.x, ax);
    y4.y = 0.25f * h4.y + 0.75f * di * fmaf(di, xs.y, ay);
    y4.z = 0.25f * h4.z + 0.75f * di * fmaf(di, xs.z, az);
    y4.w = 0.25f * h4.w + 0.75f * di * fmaf(di, xs.w, aw);
    float4 xb;
    if (FIRST) {
      xb = y4;
    } else {
      float4 u4 = ((const float4*)U)[idx];
      xb.x = y4.x - 0.25f * u4.x;
      xb.y = y4.y - 0.25f * u4.y;
      xb.z = y4.z - 0.25f * u4.z;
      xb.w = y4.w - 0.25f * u4.w;
    }
    ((float4*)XB)[idx] = xb;
    __half2 hb0 = __floats2half2_rn(xb.x, xb.y);
    __half2 hb1 = __floats2half2_rn(xb.z, xb.w);
    uint2 ob;
    ob.x = *(const unsigned*)&hb0;
    ob.y = *(const unsigned*)&hb1;
    ((uint2*)XBh)[idx] = ob;
  }
}

// z <- proj_L21( z + 2*(a*xb[r] - b*xb[c]) ), in place, Z stored fp16.
// Wave = 8 consecutive (r-sorted) edges, 2 per 16-lane group.
// xb gathers come from the fp16 shadow XBh.
template <int FIRST>
__global__ __launch_bounds__(256) void zstep_kernel(
    __half* __restrict__ Z, const __half* __restrict__ XBh,
    const EInfo* __restrict__ rcab) {
  int w = (int)((blockIdx.x * 256u + threadIdx.x) >> 6);
  int base = w * 8;
  if (base >= NE) return;
  int lane = threadIdx.x & 63;
  int g = lane >> 4, l = lane & 15;
  int e0 = base + g, e1 = base + g + 4;
  EInfo ei0 = rcab[e0];
  EInfo ei1 = rcab[e1];
  const uint2* X2 = (const uint2*)XBh;
  uint2* Z2 = (uint2*)Z;
  int zi0 = e0 * 16 + l, zi1 = e1 * 16 + l;
  uint2 xr0u = X2[ei0.r * 16 + l];
  uint2 xc0u = X2[ei0.c * 16 + l];
  uint2 xr1u = X2[ei1.r * 16 + l];
  uint2 xc1u = X2[ei1.c * 16 + l];
  float2 xr0a = __half22float2(*(const __half2*)&xr0u.x);
  float2 xr0b = __half22float2(*(const __half2*)&xr0u.y);
  float2 xc0a = __half22float2(*(const __half2*)&xc0u.x);
  float2 xc0b = __half22float2(*(const __half2*)&xc0u.y);
  float2 xr1a = __half22float2(*(const __half2*)&xr1u.x);
  float2 xr1b = __half22float2(*(const __half2*)&xr1u.y);
  float2 xc1a = __half22float2(*(const __half2*)&xc1u.x);
  float2 xc1b = __half22float2(*(const __half2*)&xc1u.y);
  float zx0, zy0, zz0, zw0, zx1, zy1, zz1, zw1;
  if (FIRST) {
    zx0 = zy0 = zz0 = zw0 = 0.f;
    zx1 = zy1 = zz1 = zw1 = 0.f;
  } else {
    uint2 zu0 = Z2[zi0];
    uint2 zu1 = Z2[zi1];
    float2 f0 = __half22float2(*(const __half2*)&zu0.x);
    float2 f1 = __half22float2(*(const __half2*)&zu0.y);
    zx0 = f0.x; zy0 = f0.y; zz0 = f1.x; zw0 = f1.y;
    f0 = __half22float2(*(const __half2*)&zu1.x);
    f1 = __half22float2(*(const __half2*)&zu1.y);
    zx1 = f0.x; zy1 = f0.y; zz1 = f1.x; zw1 = f1.y;
  }
  zx0 += 2.0f * (ei0.a * xr0a.x - ei0.b * xc0a.x);
  zy0 += 2.0f * (ei0.a * xr0a.y - ei0.b * xc0a.y);
  zz0 += 2.0f * (ei0.a * xr0b.x - ei0.b * xc0b.x);
  zw0 += 2.0f * (ei0.a * xr0b.y - ei0.b * xc0b.y);
  zx1 += 2.0f * (ei1.a * xr1a.x - ei1.b * xc1a.x);
  zy1 += 2.0f * (ei1.a * xr1a.y - ei1.b * xc1a.y);
  zz1 += 2.0f * (ei1.a * xr1b.x - ei1.b * xc1b.x);
  zw1 += 2.0f * (ei1.a * xr1b.y - ei1.b * xc1b.y);
  float s0 = zx0 * zx0 + zy0 * zy0 + zz0 * zz0 + zw0 * zw0;
  float s1 = zx1 * zx1 + zy1 * zy1 + zz1 * zz1 + zw1 * zw1;
  s0 += __shfl_xor(s0, 1, 64); s1 += __shfl_xor(s1, 1, 64);
  s0 += __shfl_xor(s0, 2, 64); s1 += __shfl_xor(s1, 2, 64);
  s0 += __shfl_xor(s0, 4, 64); s1 += __shfl_xor(s1, 4, 64);
  s0 += __shfl_xor(s0, 8, 64); s1 += __shfl_xor(s1, 8, 64);
  float rn0 = sqrtf(s0), rn1 = sqrtf(s1);
  float sc0 = (rn0 > LAM) ? (LAM / rn0) : 1.0f;
  float sc1 = (rn1 > LAM) ? (LAM / rn1) : 1.0f;
  __half2 a0 = __floats2half2_rn(sc0 * zx0, sc0 * zy0);
  __half2 b0 = __floats2half2_rn(sc0 * zz0, sc0 * zw0);
  __half2 a1 = __floats2half2_rn(sc1 * zx1, sc1 * zy1);
  __half2 b1 = __floats2half2_rn(sc1 * zz1, sc1 * zw1);
  uint2 o0, o1;
  o0.x = *(const unsigned*)&a0; o0.y = *(const unsigned*)&b0;
  o1.x = *(const unsigned*)&a1; o1.y = *(const unsigned*)&b1;
  Z2[zi0] = o0;
  Z2[zi1] = o1;
}

// u_new = dis_i * (sum_{r-side} z_e - sum_{c-side} z_e);  unified walk:
// t<lenR -> edge id rb+t (no metadata, + sign); else cEnt (gather, - sign).
// y = XB + 0.25*U_old (reconstructed); Xout = y - 0.25*u_new; U <- u_new;
// XH <- fp16(Xout) shadow for the next adj (skipped on LAST).
template <int FIRST, int LAST>
__global__ __launch_bounds__(256) void incT_kernel(
    const __half* __restrict__ Z, const float* __restrict__ XB,
    const float* __restrict__ dis,
    const int* __restrict__ rPtr, const int* __restrict__ cPtr,
    const int2* __restrict__ cEnt,
    float* __restrict__ U, float* __restrict__ Xout,
    __half* __restrict__ XH) {
  int w = (int)((blockIdx.x * 256u + threadIdx.x) >> 6);
  if (w >= NN) return;
  int lane = threadIdx.x & 63;
  int g = lane >> 4, l = lane & 15;
  const uint2* Z2 = (const uint2*)Z;
  int rb = rPtr[w], lenR = rPtr[w + 1] - rb;
  int cb = cPtr[w], lenC = cPtr[w + 1] - cb;
  int total = lenR + lenC;
  int lc1 = lenC > 0 ? lenC - 1 : 0;
  float ax = 0.f, ay = 0.f, az = 0.f, aw = 0.f;

#define INCT_FETCH(T, E, SG)                                         \
  {                                                                  \
    int tc = (T) - lenR; tc = tc > 0 ? tc : 0; tc = tc < lc1 ? tc : lc1; \
    int2 ce = cEnt[cb + tc];                                         \
    bool isR = (T) < lenR;                                           \
    E = isR ? (rb + (T)) : ce.y;                                     \
    SG = isR ? 1.0f : -1.0f;                                         \
  }

  int t = g;
  for (; t + 12 < total; t += 16) {
    int e0, e1, e2, e3; float s0, s1, s2, s3;
    INCT_FETCH(t, e0, s0);
    INCT_FETCH(t + 4, e1, s1);
    INCT_FETCH(t + 8, e2, s2);
    INCT_FETCH(t + 12, e3, s3);
    uint2 zu0 = Z2[e0 * 16 + l];
    uint2 zu1 = Z2[e1 * 16 + l];
    uint2 zu2 = Z2[e2 * 16 + l];
    uint2 zu3 = Z2[e3 * 16 + l];
    float2 a0 = __half22float2(*(const __half2*)&zu0.x);
    float2 b0 = __half22float2(*(const __half2*)&zu0.y);
    float2 a1 = __half22float2(*(const __half2*)&zu1.x);
    float2 b1 = __half22float2(*(const __half2*)&zu1.y);
    float2 a2 = __half22float2(*(const __half2*)&zu2.x);
    float2 b2 = __half22float2(*(const __half2*)&zu2.y);
    float2 a3 = __half22float2(*(const __half2*)&zu3.x);
    float2 b3 = __half22float2(*(const __half2*)&zu3.y);
    ax = fmaf(s0, a0.x, ax); ay = fmaf(s0, a0.y, ay);
    az = fmaf(s0, b0.x, az); aw = fmaf(s0, b0.y, aw);
    ax = fmaf(s1, a1.x, ax); ay = fmaf(s1, a1.y, ay);
    az = fmaf(s1, b1.x, az); aw = fmaf(s1, b1.y, aw);
    ax = fmaf(s2, a2.x, ax); ay = fmaf(s2, a2.y, ay);
    az = fmaf(s2, b2.x, az); aw = fmaf(s2, b2.y, aw);
    ax = fmaf(s3, a3.x, ax); ay = fmaf(s3, a3.y, ay);
    az = fmaf(s3, b3.x, az); aw = fmaf(s3, b3.y, aw);
  }
  for (; t < total; t += 4) {
    int e0; float s0;
    INCT_FETCH(t, e0, s0);
    uint2 zu0 = Z2[e0 * 16 + l];
    float2 a0 = __half22float2(*(const __half2*)&zu0.x);
    float2 b0 = __half22float2(*(const __half2*)&zu0.y);
    ax = fmaf(s0, a0.x, ax); ay = fmaf(s0, a0.y, ay);
    az = fmaf(s0, b0.x, az); aw = fmaf(s0, b0.y, aw);
  }
#undef INCT_FETCH

  ax += __shfl_xor(ax, 16, 64); ay += __shfl_xor(ay, 16, 64);
  az += __shfl_xor(az, 16, 64); aw += __shfl_xor(aw, 16, 64);
  ax += __shfl_xor(ax, 32, 64); ay += __shfl_xor(ay, 32, 64);
  az += __shfl_xor(az, 32, 64); aw += __shfl_xor(aw, 32, 64);
  if (g == 0) {
    float di = dis[w];
    int idx = w * 16 + l;
    float4 u;
    u.x = di * ax; u.y = di * ay; u.z = di * az; u.w = di * aw;
    float4 xb = ((const float4*)XB)[idx];
    float4 y4;
    if (FIRST) {
      y4 = xb;  // U_old == 0
    } else {
      float4 uo = ((const float4*)U)[idx];
      y4.x = xb.x + 0.25f * uo.x;
      y4.y = xb.y + 0.25f * uo.y;
      y4.z = xb.z + 0.25f * uo.z;
      y4.w = xb.w + 0.25f * uo.w;
    }
    if (!LAST) ((float4*)U)[idx] = u;  // dead after final step
    float4 o;
    o.x = y4.x - 0.25f * u.x;
    o.y = y4.y - 0.25f * u.y;
    o.z = y4.z - 0.25f * u.z;
    o.w = y4.w - 0.25f * u.w;
    ((float4*)Xout)[idx] = o;
    if (!LAST) {
      __half2 h0 = __floats2half2_rn(o.x, o.y);
      __half2 h1 = __floats2half2_rn(o.z, o.w);
      uint2 oh;
      oh.x = *(const unsigned*)&h0;
      oh.y = *(const unsigned*)&h1;
      ((uint2*)XH)[idx] = oh;
    }
  }
}

// ---------------- launch ----------------

extern "C" void kernel_launch(void* const* d_in, const int* in_sizes, int n_in,
                              void* d_out, int out_size, void* d_ws, size_t ws_size,
                              hipStream_t stream) {
  const float* x  = (const float*)d_in[0];
  const int* esrc = (const int*)d_in[1];
  const int* edst = (const int*)d_in[2];
  float* out = (float*)d_out;

  char* base = (char*)d_ws;
  size_t off = 0;
  auto carve = [&](size_t bytes) -> void* {
    void* p = base + off;
    off += (bytes + 255) & ~(size_t)255;
    return p;
  };
  __half* Z   = (__half*)carve((size_t)NE * 64 * 2);  // 102.4 MB carry state z
  float* XK   = (float*)carve((size_t)NN * 64 * 4);   // current xk (fp32 master)
  float* XB   = (float*)carve((size_t)NN * 64 * 4);   // x_bar (fp32 master)
  float* U    = (float*)carve((size_t)NN * 64 * 4);   // incT(z), reused next step
  __half* XH  = (__half*)carve((size_t)NN * 64 * 2);  // fp16 shadow of xk
  __half* XBh = (__half*)carve((size_t)NN * 64 * 2);  // fp16 shadow of x_bar
  float* dis = (float*)carve((size_t)NN * 4);
  int* cR  = (int*)carve((size_t)NN * 4);
  int* cC  = (int*)carve((size_t)NN * 4);
  int* rPtr = (int*)carve((size_t)(NN + 1) * 4);
  int* cPtr = (int*)carve((size_t)(NN + 1) * 4);
  int* urR = (int*)carve((size_t)NN * 4);
  int* uC  = (int*)carve((size_t)NN * 4);
  int* bsum = (int*)carve((size_t)SCAN_NB * 4);
  int* boff = (int*)carve((size_t)SCAN_NB * 4);
  EInfo* rcab = (EInfo*)carve((size_t)NE * 16);      // 12.8 MB sorted edges
  int2* cEnt = (int2*)carve((size_t)NE * 8);         // 6.4 MB c-side CSR
  (void)ws_size; (void)in_sizes; (void)n_in; (void)out_size;

  hipMemsetAsync(cR, 0, NN * 4, stream);
  hipMemsetAsync(cC, 0, NN * 4, stream);

  const int edgeGrid = (NE + 255) / 256;
  countRC_kernel<<<edgeGrid, 256, 0, stream>>>(esrc, edst, cR, cC);
  dis_kernel<<<(NN + 255) / 256, 256, 0, stream>>>(cR, cC, dis);
  half_copy_kernel<<<(NN * 16 + 255) / 256, 256, 0, stream>>>(x, XH);
  scanA_kernel<<<SCAN_NB, 256, 0, stream>>>(cR, bsum);
  scanB_kernel<<<1, 256, 0, stream>>>(bsum, boff);
  scanC_kernel<<<SCAN_NB, 256, 0, stream>>>(cR, boff, rPtr, urR);
  scanA_kernel<<<SCAN_NB, 256, 0, stream>>>(cC, bsum);
  scanB_kernel<<<1, 256, 0, stream>>>(bsum, boff);
  scanC_kernel<<<SCAN_NB, 256, 0, stream>>>(cC, boff, cPtr, uC);
  sortscatter_kernel<<<edgeGrid, 256, 0, stream>>>(esrc, edst, dis, urR, uC,
                                                   rcab, cEnt);

  const int nodeBlocks = NN * 64 / 256;       // 12500 (one wave/node, exact)
  const int edgeBlocks = (NE / 8) * 64 / 256; // 25000 (wave = 8 edges, exact)

  for (int k = 0; k < KS; ++k) {
    const float* xk = (k == 0) ? x : XK;
    if (k == 0)
      adj_kernel<1><<<nodeBlocks, 256, 0, stream>>>(xk, XH, x, U, dis, rPtr,
                                                    cPtr, cEnt, rcab, XB, XBh);
    else
      adj_kernel<0><<<nodeBlocks, 256, 0, stream>>>(xk, XH, x, U, dis, rPtr,
                                                    cPtr, cEnt, rcab, XB, XBh);

    if (k == 0)
      zstep_kernel<1><<<edgeBlocks, 256, 0, stream>>>(Z, XBh, rcab);
    else
      zstep_kernel<0><<<edgeBlocks, 256, 0, stream>>>(Z, XBh, rcab);

    float* xout = (k == KS - 1) ? out : XK;
    if (k == 0)
      incT_kernel<1, 0><<<nodeBlocks, 256, 0, stream>>>(Z, XB, dis, rPtr, cPtr,
                                                        cEnt, U, xout, XH);
    else if (k == KS - 1)
      incT_kernel<0, 1><<<nodeBlocks, 256, 0, stream>>>(Z, XB, dis, rPtr, cPtr,
                                                        cEnt, U, xout, XH);
    else
      incT_kernel<0, 0><<<nodeBlocks, 256, 0, stream>>>(Z, XB, dis, rPtr, cPtr,
                                                        cEnt, U, xout, XH);
  }
}